// Round 2
// baseline (1895.032 us; speedup 1.0000x reference)
//
#include <hip/hip_runtime.h>
#include <hip/hip_bf16.h>

typedef __hip_bfloat16 bf16;

#define NN   16
#define CIN  512
#define HH   56
#define WW   56
#define BB   (NN*WW)     /* 896 */
#define OO   1024
#define GG   8
#define RL   111         /* 2K-1 */
#define EPSV 1e-5f

static __device__ __forceinline__ float u2f(unsigned short u){
  union { unsigned int i; float f; } x; x.i = ((unsigned int)u) << 16; return x.f;
}
static __device__ __forceinline__ unsigned short f2u(float f){
  union { float f; unsigned int i; } x; x.f = f;
  unsigned int i = x.i;
  unsigned int r = i + 0x7FFFu + ((i >> 16) & 1u);   // RNE
  return (unsigned short)(r >> 16);
}
static __device__ __forceinline__ float ldin(const void* p, size_t i, bool f32){
  return f32 ? ((const float*)p)[i] : u2f(((const unsigned short*)p)[i]);
}

// ---------------- dtype probe + stat zeroing ----------------
__global__ void kDetect(const void* __restrict__ x, float* __restrict__ stats, int* __restrict__ flag){
  const int t = threadIdx.x;     // 128 threads
  if (t < 64) stats[t] = 0.f;
  unsigned short u = ((const unsigned short*)x)[t];
  int e = (u >> 7) & 0xFF;
  int bad = (e < 100 || e > 140) ? 1 : 0;
  __shared__ int cnt;
  if (t == 0) cnt = 0;
  __syncthreads();
  if (bad) atomicAdd(&cnt, 1);
  __syncthreads();
  if (t == 0) *flag = (cnt > 16) ? 1 : 0;   // 1 => inputs are fp32
}

// ---------------- transpose x (N,C,H,W) -> xt[b=(n*W+w)][c][h] (canonical bf16) ----------------
__global__ __launch_bounds__(256) void kTrans(const void* __restrict__ x, bf16* __restrict__ xt,
                                              const int* __restrict__ dflag){
  const bool f32 = (*dflag != 0);
  const int c = blockIdx.x, n = blockIdx.y;
  __shared__ unsigned short tile[HH][WW+2];
  const size_t base = ((size_t)(n*CIN + c))*HH*WW;
  for (int idx = threadIdx.x; idx < HH*WW; idx += 256)
    tile[idx / WW][idx % WW] = f2u(ldin(x, base + idx, f32));
  __syncthreads();
  unsigned short* dst = (unsigned short*)xt;
  for (int idx = threadIdx.x; idx < HH*WW; idx += 256){
    int w = idx / HH, h = idx - w*HH;
    dst[((size_t)((n*WW + w)*CIN + c))*HH + h] = tile[h][w];
  }
}

// ---------------- qkv[b][o][h] = sum_c w[o][c] * xt[b][c][h] ----------------
__global__ __launch_bounds__(256) void kGemmQKV(const void* __restrict__ wq, const bf16* __restrict__ xt,
                                                bf16* __restrict__ qkv, const int* __restrict__ dflag){
  const bool f32 = (*dflag != 0);
  const int b  = blockIdx.y;
  const int o0 = blockIdx.x * 64;
  __shared__ float Wt[16][64];
  __shared__ float Xt[16][64];
  const int t  = threadIdx.x;
  const int tx = t & 15, ty = t >> 4;
  float acc[4][4] = {};
  const int lo = t & 63, lkq = t >> 6;   // W-tile load: o=lo, k=lkq*4..+3
  const int lk = t >> 4, lhq = t & 15;   // X-tile load: k=lk, h=lhq*4..+3
  const size_t wofs = (size_t)(o0 + lo)*CIN + lkq*4;
  const unsigned short* xp = (const unsigned short*)xt + (size_t)b*CIN*HH;
  for (int k0 = 0; k0 < CIN; k0 += 16){
    if (f32){
      const float4 fw = *(const float4*)((const float*)wq + wofs + k0);
      Wt[lkq*4+0][lo] = fw.x; Wt[lkq*4+1][lo] = fw.y;
      Wt[lkq*4+2][lo] = fw.z; Wt[lkq*4+3][lo] = fw.w;
    } else {
      const ushort4 uw = *(const ushort4*)((const unsigned short*)wq + wofs + k0);
      Wt[lkq*4+0][lo] = u2f(uw.x); Wt[lkq*4+1][lo] = u2f(uw.y);
      Wt[lkq*4+2][lo] = u2f(uw.z); Wt[lkq*4+3][lo] = u2f(uw.w);
    }
    float x0=0.f,x1=0.f,x2=0.f,x3=0.f;
    if (lhq < 14){
      ushort4 ux = *(const ushort4*)(xp + (size_t)(k0 + lk)*HH + lhq*4);
      x0=u2f(ux.x); x1=u2f(ux.y); x2=u2f(ux.z); x3=u2f(ux.w);
    }
    Xt[lk][lhq*4+0]=x0; Xt[lk][lhq*4+1]=x1; Xt[lk][lhq*4+2]=x2; Xt[lk][lhq*4+3]=x3;
    __syncthreads();
    #pragma unroll
    for (int k = 0; k < 16; ++k){
      const float4 a  = *(const float4*)&Wt[k][ty*4];
      const float4 bb = *(const float4*)&Xt[k][tx*4];
      const float av[4] = {a.x,a.y,a.z,a.w};
      const float bv[4] = {bb.x,bb.y,bb.z,bb.w};
      #pragma unroll
      for (int mo = 0; mo < 4; ++mo)
        #pragma unroll
        for (int mh = 0; mh < 4; ++mh)
          acc[mo][mh] += av[mo]*bv[mh];
    }
    __syncthreads();
  }
  const int h = tx*4;
  if (h < HH){
    unsigned short* dst = (unsigned short*)qkv + (size_t)b*OO*HH;
    #pragma unroll
    for (int mo = 0; mo < 4; ++mo){
      const int o = o0 + ty*4 + mo;
      *(ushort4*)(dst + (size_t)o*HH + h) =
        make_ushort4(f2u(acc[mo][0]), f2u(acc[mo][1]), f2u(acc[mo][2]), f2u(acc[mo][3]));
    }
  }
}

// ---------------- per-channel BN stats over [b][o][h] (axes b,h) -> scale/shift ----------------
__global__ __launch_bounds__(256) void kStatO(const bf16* __restrict__ t, const void* __restrict__ gamma,
                                              const void* __restrict__ beta,
                                              float* __restrict__ sc, float* __restrict__ sh,
                                              const int* __restrict__ dflag){
  const bool f32 = (*dflag != 0);
  const int o = blockIdx.x;
  const unsigned short* p = (const unsigned short*)t;
  float s = 0.f, sq = 0.f;
  for (int idx = threadIdx.x; idx < BB*HH; idx += 256){
    int b = idx / HH, h = idx - b*HH;
    float v = u2f(p[((size_t)b*OO + o)*HH + h]);
    s += v; sq += v*v;
  }
  #pragma unroll
  for (int off = 32; off > 0; off >>= 1){ s += __shfl_down(s, off); sq += __shfl_down(sq, off); }
  __shared__ float rs[4], rq[4];
  const int wid = threadIdx.x >> 6;
  if ((threadIdx.x & 63) == 0){ rs[wid] = s; rq[wid] = sq; }
  __syncthreads();
  if (threadIdx.x == 0){
    float S = rs[0]+rs[1]+rs[2]+rs[3], Q = rq[0]+rq[1]+rq[2]+rq[3];
    const float cnt = (float)(BB*HH);
    float mean = S / cnt;
    float var  = Q / cnt - mean*mean;
    float scale = ldin(gamma, o, f32) * rsqrtf(var + EPSV);
    sc[o] = scale; sh[o] = ldin(beta, o, f32) - mean*scale;
  }
}

// ---------------- score pass A: accumulate BN2 stats for qk/qr/kr ----------------
__global__ __launch_bounds__(256) void kS1(const bf16* __restrict__ qkv, const void* __restrict__ rel,
                                           const float* __restrict__ sc1, const float* __restrict__ sh1,
                                           float* __restrict__ s2sum, float* __restrict__ s2sq,
                                           const int* __restrict__ dflag){
  const bool f32 = (*dflag != 0);
  const int b = blockIdx.x, g = blockIdx.y;
  __shared__ float qs[32][HH];
  __shared__ float ks[32][HH];
  __shared__ float rq[32][RL+1];
  __shared__ float rk[32][RL+1];
  const int t = threadIdx.x;
  {
    const unsigned short* qp = (const unsigned short*)qkv + (size_t)(b*OO + g*128)*HH;
    for (int idx = t; idx < 64*HH; idx += 256){
      int c = idx / HH, h = idx - c*HH;
      int o = g*128 + c;
      float v = u2f(qp[(size_t)c*HH + h]) * sc1[o] + sh1[o];
      if (c < 32) qs[c][h] = v; else ks[c-32][h] = v;
    }
    for (int idx = t; idx < 64*RL; idx += 256){
      int c = idx / RL, d = idx - c*RL;
      float v = ldin(rel, (size_t)c*RL + d, f32);
      if (c < 32) rq[c][d] = v; else rk[c-32][d] = v;
    }
  }
  __syncthreads();
  float s[3] = {0.f,0.f,0.f}, q2[3] = {0.f,0.f,0.f};
  if (t < 196){
    const int i0 = (t/14)*4, j0 = (t - (t/14)*14)*4;
    float aqk[16] = {}, aqr[16] = {}, akr[16] = {};
    const int dq = i0 - j0 + 52, dk = j0 - i0 + 52;
    for (int c = 0; c < 32; ++c){
      const float4 qa = *(const float4*)&qs[c][i0];
      const float4 kb = *(const float4*)&ks[c][j0];
      const float qv[4] = {qa.x,qa.y,qa.z,qa.w};
      const float kv[4] = {kb.x,kb.y,kb.z,kb.w};
      float rqv[7], rkv[7];
      #pragma unroll
      for (int m = 0; m < 7; ++m){ rqv[m] = rq[c][dq+m]; rkv[m] = rk[c][dk+m]; }
      #pragma unroll
      for (int di = 0; di < 4; ++di)
        #pragma unroll
        for (int dj = 0; dj < 4; ++dj){
          aqk[di*4+dj] += qv[di]*kv[dj];
          aqr[di*4+dj] += qv[di]*rqv[3+di-dj];
          akr[di*4+dj] += kv[dj]*rkv[3+dj-di];
        }
    }
    #pragma unroll
    for (int m = 0; m < 16; ++m){
      s[0]+=aqk[m]; q2[0]+=aqk[m]*aqk[m];
      s[1]+=aqr[m]; q2[1]+=aqr[m]*aqr[m];
      s[2]+=akr[m]; q2[2]+=akr[m]*akr[m];
    }
  }
  #pragma unroll
  for (int off = 32; off > 0; off >>= 1)
    #pragma unroll
    for (int m = 0; m < 3; ++m){ s[m]+=__shfl_down(s[m],off); q2[m]+=__shfl_down(q2[m],off); }
  __shared__ float red[6][4];
  const int wid = t >> 6;
  if ((t & 63) == 0){
    #pragma unroll
    for (int m = 0; m < 3; ++m){ red[m][wid]=s[m]; red[3+m][wid]=q2[m]; }
  }
  __syncthreads();
  if (t < 6){
    float v = red[t][0]+red[t][1]+red[t][2]+red[t][3];
    int m = t % 3;
    int ch = m*8 + g;                       // stacked channel = s*8 + g
    atomicAdd((t >= 3) ? &s2sq[ch] : &s2sum[ch], v);
  }
}

__global__ void kF2(const float* __restrict__ s2sum, const float* __restrict__ s2sq,
                    const void* __restrict__ gs, const void* __restrict__ bs,
                    float* __restrict__ sc2, float* __restrict__ sh2,
                    const int* __restrict__ dflag){
  const bool f32 = (*dflag != 0);
  const int ch = threadIdx.x;
  if (ch < 24){
    const float cnt = (float)BB * (float)(HH*HH);
    float mean = s2sum[ch] / cnt;
    float var  = s2sq[ch] / cnt - mean*mean;
    float scale = ldin(gs, ch, f32) * rsqrtf(var + EPSV);
    sc2[ch] = scale; sh2[ch] = ldin(bs, ch, f32) - mean*scale;
  }
}

// ---------------- pass B: recompute scores, BN2, softmax, sv/sve ----------------
__global__ __launch_bounds__(256) void kAttn(const bf16* __restrict__ qkv, const void* __restrict__ rel,
                                             const float* __restrict__ sc1, const float* __restrict__ sh1,
                                             const float* __restrict__ sc2, const float* __restrict__ sh2,
                                             bf16* __restrict__ outr, const int* __restrict__ dflag){
  const bool f32 = (*dflag != 0);
  const int b = blockIdx.x, g = blockIdx.y;
  __shared__ __align__(16) unsigned char smem[61376];
  float (*qs)[HH]          = (float(*)[HH])(smem);                 // [32][56]  phase1
  float (*ks)[HH]          = (float(*)[HH])(smem + 7168);          // [32][56]  phase1
  float (*rq)[RL+1]        = (float(*)[RL+1])(smem + 14336);       // [32][112] phase1
  float (*rk)[RL+1]        = (float(*)[RL+1])(smem + 28672);       // [32][112] phase1
  float (*pT)[HH]          = (float(*)[HH])(smem);                 // [56][56]  phase3
  unsigned short (*vT)[68] = (unsigned short(*)[68])(smem + 12544);// [56][68]  phase3
  float (*rv)[RL+1]        = (float(*)[RL+1])(smem + 20160);       // [64][112] phase3
  float (*sim)[HH]         = (float(*)[HH])(smem + 48832);         // [56][56]  persistent
  const int t = threadIdx.x;
  {
    const unsigned short* qp = (const unsigned short*)qkv + (size_t)(b*OO + g*128)*HH;
    for (int idx = t; idx < 64*HH; idx += 256){
      int c = idx / HH, h = idx - c*HH;
      int o = g*128 + c;
      float v = u2f(qp[(size_t)c*HH + h]) * sc1[o] + sh1[o];
      if (c < 32) qs[c][h] = v; else ks[c-32][h] = v;
    }
    for (int idx = t; idx < 64*RL; idx += 256){
      int c = idx / RL, d = idx - c*RL;
      float v = ldin(rel, (size_t)c*RL + d, f32);
      if (c < 32) rq[c][d] = v; else rk[c-32][d] = v;
    }
  }
  __syncthreads();
  if (t < 196){
    const int i0 = (t/14)*4, j0 = (t - (t/14)*14)*4;
    float aqk[16] = {}, aqr[16] = {}, akr[16] = {};
    const int dq = i0 - j0 + 52, dk = j0 - i0 + 52;
    for (int c = 0; c < 32; ++c){
      const float4 qa = *(const float4*)&qs[c][i0];
      const float4 kb = *(const float4*)&ks[c][j0];
      const float qv[4] = {qa.x,qa.y,qa.z,qa.w};
      const float kv[4] = {kb.x,kb.y,kb.z,kb.w};
      float rqv[7], rkv[7];
      #pragma unroll
      for (int m = 0; m < 7; ++m){ rqv[m] = rq[c][dq+m]; rkv[m] = rk[c][dk+m]; }
      #pragma unroll
      for (int di = 0; di < 4; ++di)
        #pragma unroll
        for (int dj = 0; dj < 4; ++dj){
          aqk[di*4+dj] += qv[di]*kv[dj];
          aqr[di*4+dj] += qv[di]*rqv[3+di-dj];
          akr[di*4+dj] += kv[dj]*rkv[3+dj-di];
        }
    }
    const float scqk=sc2[g],    shqk=sh2[g];
    const float scqr=sc2[8+g],  shqr=sh2[8+g];
    const float sckr=sc2[16+g], shkr=sh2[16+g];
    #pragma unroll
    for (int di = 0; di < 4; ++di)
      #pragma unroll
      for (int dj = 0; dj < 4; ++dj)
        sim[i0+di][j0+dj] = aqk[di*4+dj]*scqk+shqk + aqr[di*4+dj]*scqr+shqr + akr[di*4+dj]*sckr+shkr;
  }
  __syncthreads();
  // phase-3 loads overwrite dead phase-1 region
  {
    const unsigned short* vp = (const unsigned short*)qkv + (size_t)(b*OO + g*128 + 64)*HH;
    for (int idx = t; idx < 64*HH; idx += 256){
      int c = idx / HH, j = idx - c*HH;
      int o = g*128 + 64 + c;
      float v = u2f(vp[(size_t)c*HH + j]) * sc1[o] + sh1[o];
      vT[j][c] = f2u(v);
    }
    for (int idx = t; idx < 64*RL; idx += 256){
      int c = idx / RL, d = idx - c*RL;
      rv[c][d] = ldin(rel, (size_t)(64 + c)*RL + d, f32);
    }
  }
  if (t < 224){
    const int r = t >> 2, l4 = t & 3;
    float pvv[14]; float mx = -1e30f;
    #pragma unroll
    for (int m = 0; m < 14; ++m){ pvv[m] = sim[r][l4 + 4*m]; mx = fmaxf(mx, pvv[m]); }
    mx = fmaxf(mx, __shfl_xor(mx, 1)); mx = fmaxf(mx, __shfl_xor(mx, 2));
    float sm = 0.f;
    #pragma unroll
    for (int m = 0; m < 14; ++m){ pvv[m] = __expf(pvv[m] - mx); sm += pvv[m]; }
    sm += __shfl_xor(sm, 1); sm += __shfl_xor(sm, 2);
    const float inv = 1.f / sm;
    #pragma unroll
    for (int m = 0; m < 14; ++m) pT[l4 + 4*m][r] = pvv[m]*inv;
  }
  __syncthreads();
  if (t < 224){
    const int c0 = (t/14)*4, i0 = (t - (t/14)*14)*4;
    float asv[16] = {}, asve[16] = {};
    float win[4][4];
    #pragma unroll
    for (int dc = 0; dc < 4; ++dc)
      #pragma unroll
      for (int m = 0; m < 4; ++m) win[dc][m] = rv[c0+dc][i0+55+m];
    for (int j = 0; j < 56; ++j){
      const float4  p4 = *(const float4*)&pT[j][i0];
      const ushort4 uv = *(const ushort4*)&vT[j][c0];
      const float pp[4] = {p4.x,p4.y,p4.z,p4.w};
      const float vv[4] = {u2f(uv.x),u2f(uv.y),u2f(uv.z),u2f(uv.w)};
      #pragma unroll
      for (int dc = 0; dc < 4; ++dc)
        #pragma unroll
        for (int di = 0; di < 4; ++di){
          asv[dc*4+di]  += vv[dc]*pp[di];
          asve[dc*4+di] += win[dc][di]*pp[di];
        }
      int nb = i0 - j + 54; if (nb < 0) nb = 0;
      #pragma unroll
      for (int dc = 0; dc < 4; ++dc){
        win[dc][3]=win[dc][2]; win[dc][2]=win[dc][1]; win[dc][1]=win[dc][0];
        win[dc][0] = rv[c0+dc][nb];
      }
    }
    unsigned short* op = (unsigned short*)outr + (size_t)b*OO*HH;
    #pragma unroll
    for (int dc = 0; dc < 4; ++dc){
      const int och = (g*64 + c0 + dc)*2;
      *(ushort4*)(op + (size_t)och*HH + i0) =
        make_ushort4(f2u(asv[dc*4+0]),  f2u(asv[dc*4+1]),  f2u(asv[dc*4+2]),  f2u(asv[dc*4+3]));
      *(ushort4*)(op + (size_t)(och+1)*HH + i0) =
        make_ushort4(f2u(asve[dc*4+0]), f2u(asve[dc*4+1]), f2u(asve[dc*4+2]), f2u(asve[dc*4+3]));
    }
  }
}

// ---------------- BN3 + pair-sum + transpose to (N,512,H,W) ----------------
__global__ __launch_bounds__(256) void kOut(const bf16* __restrict__ outr, const float* __restrict__ sc3,
                                            const float* __restrict__ sh3, void* __restrict__ out,
                                            const int* __restrict__ dflag){
  const bool f32 = (*dflag != 0);
  const int p = blockIdx.x, n = blockIdx.y;
  __shared__ float tile[HH][WW+1];
  const unsigned short* ip = (const unsigned short*)outr;
  const float s0 = sc3[2*p], h0 = sh3[2*p], s1 = sc3[2*p+1], h1 = sh3[2*p+1];
  for (int idx = threadIdx.x; idx < HH*WW; idx += 256){
    int w = idx / HH, h = idx - w*HH;
    size_t base = ((size_t)((n*WW + w)*OO) + 2*p)*HH + h;
    float a = u2f(ip[base]);
    float c = u2f(ip[base + HH]);
    tile[h][w] = a*s0 + h0 + c*s1 + h1;
  }
  __syncthreads();
  const size_t obase = ((size_t)(n*512 + p))*HH*WW;
  for (int idx = threadIdx.x; idx < HH*WW; idx += 256){
    int h = idx / WW, w = idx - h*WW;
    float v = tile[h][w];
    if (f32) ((float*)out)[obase + idx] = v;
    else     ((unsigned short*)out)[obase + idx] = f2u(v);
  }
}

extern "C" void kernel_launch(void* const* d_in, const int* in_sizes, int n_in,
                              void* d_out, int out_size, void* d_ws, size_t ws_size,
                              hipStream_t stream){
  (void)in_sizes; (void)n_in; (void)out_size; (void)ws_size;
  const void* x    = d_in[0];
  const void* wqkv = d_in[1];
  const void* rel  = d_in[2];
  const void* gq   = d_in[3];
  const void* bq   = d_in[4];
  const void* gs   = d_in[5];
  const void* bs   = d_in[6];
  const void* go   = d_in[7];
  const void* bo   = d_in[8];

  char* ws = (char*)d_ws;
  const size_t szA = (size_t)BB*OO*HH*2;   // 102,760,448 B
  bf16* xt   = (bf16*)ws;                  // [B][C][H]   (first 51.4 MB; dead after GEMM)
  bf16* outr = (bf16*)ws;                  // [B][O][H]   (reuses region A)
  bf16* qkv  = (bf16*)(ws + szA);          // [B][O][H]
  float* st  = (float*)(ws + 2*szA);
  float* sc1   = st;
  float* sh1   = st + 1024;
  float* sc3   = st + 2048;
  float* sh3   = st + 3072;
  float* s2sum = st + 4096;  // 24 used (32 padded)
  float* s2sq  = st + 4128;
  float* sc2   = st + 4160;
  float* sh2   = st + 4192;
  int*   flag  = (int*)(st + 4224);

  kDetect <<<1, 128, 0, stream>>>(x, s2sum, flag);
  kTrans  <<<dim3(CIN, NN), 256, 0, stream>>>(x, xt, flag);
  kGemmQKV<<<dim3(16, BB), 256, 0, stream>>>(wqkv, xt, qkv, flag);
  kStatO  <<<OO, 256, 0, stream>>>(qkv, gq, bq, sc1, sh1, flag);
  kS1     <<<dim3(BB, GG), 256, 0, stream>>>(qkv, rel, sc1, sh1, s2sum, s2sq, flag);
  kF2     <<<1, 64, 0, stream>>>(s2sum, s2sq, gs, bs, sc2, sh2, flag);
  kAttn   <<<dim3(BB, GG), 256, 0, stream>>>(qkv, rel, sc1, sh1, sc2, sh2, outr, flag);
  kStatO  <<<OO, 256, 0, stream>>>(outr, go, bo, sc3, sh3, flag);
  kOut    <<<dim3(512, NN), 256, 0, stream>>>(outr, sc3, sh3, d_out, flag);
}

// Round 3
// 1258.202 us; speedup vs baseline: 1.5061x; 1.5061x over previous
//
#include <hip/hip_runtime.h>
#include <hip/hip_bf16.h>

typedef __hip_bfloat16 bf16;
typedef __attribute__((ext_vector_type(8))) short short8;
typedef __attribute__((ext_vector_type(4))) float f32x4;

#define NN   16
#define CIN  512
#define HH   56
#define WW   56
#define BB   (NN*WW)     /* 896 */
#define OO   1024
#define GG   8
#define RL   111         /* 2K-1 */
#define EPSV 1e-5f

static __device__ __forceinline__ float u2f(unsigned short u){
  union { unsigned int i; float f; } x; x.i = ((unsigned int)u) << 16; return x.f;
}
static __device__ __forceinline__ unsigned short f2u(float f){
  union { float f; unsigned int i; } x; x.f = f;
  unsigned int i = x.i;
  unsigned int r = i + 0x7FFFu + ((i >> 16) & 1u);   // RNE
  return (unsigned short)(r >> 16);
}
static __device__ __forceinline__ float ldin(const void* p, size_t i, bool f32){
  return f32 ? ((const float*)p)[i] : u2f(((const unsigned short*)p)[i]);
}
// load 8 weights as bf16 fragment half (16B bf16 path / 32B fp32 path)
static __device__ __forceinline__ short8 ldW8(const void* wq, bool f32, size_t elem){
  if (!f32) return *(const short8*)((const unsigned short*)wq + elem);
  const float* p = (const float*)wq + elem;
  float4 a = *(const float4*)p;
  float4 b = *(const float4*)(p + 4);
  short8 r;
  r[0]=(short)f2u(a.x); r[1]=(short)f2u(a.y); r[2]=(short)f2u(a.z); r[3]=(short)f2u(a.w);
  r[4]=(short)f2u(b.x); r[5]=(short)f2u(b.y); r[6]=(short)f2u(b.z); r[7]=(short)f2u(b.w);
  return r;
}

// ---------------- dtype probe + stat zeroing ----------------
__global__ void kDetect(const void* __restrict__ x, float* __restrict__ stats, int* __restrict__ flag){
  const int t = threadIdx.x;     // 128 threads
  if (t < 64) stats[t] = 0.f;
  unsigned short u = ((const unsigned short*)x)[t];
  int e = (u >> 7) & 0xFF;
  int bad = (e < 100 || e > 140) ? 1 : 0;
  __shared__ int cnt;
  if (t == 0) cnt = 0;
  __syncthreads();
  if (bad) atomicAdd(&cnt, 1);
  __syncthreads();
  if (t == 0) *flag = (cnt > 16) ? 1 : 0;   // 1 => inputs are fp32
}

// ---------------- transpose x (N,C,H,W) -> xtk[b=(n*W+w)][h][c] (c contiguous, bf16) ----------------
__global__ __launch_bounds__(256) void kTrans(const void* __restrict__ x, bf16* __restrict__ xtk,
                                              const int* __restrict__ dflag){
  const bool f32 = (*dflag != 0);
  const int h  = blockIdx.x;       // 56
  const int cg = blockIdx.y;       // 4 groups of 128 channels
  const int n  = blockIdx.z;       // 16
  __shared__ unsigned short tile[128][58];   // stride 58 ushorts -> 29-bank stride, conflict-free
  // read: x[n][cg*128+ci][h][w], w contiguous
  const size_t rbase = (((size_t)n*CIN + cg*128)*HH + h)*WW;
  for (int idx = threadIdx.x; idx < 128*WW; idx += 256){
    int ci = idx / WW, w = idx - ci*WW;
    tile[ci][w] = f2u(ldin(x, rbase + (size_t)ci*HH*WW + w, f32));
  }
  __syncthreads();
  // write: xtk[(n*WW+w)][h][cg*128+ci], ci contiguous
  unsigned short* dst = (unsigned short*)xtk;
  for (int idx = threadIdx.x; idx < WW*128; idx += 256){
    int w = idx >> 7, ci = idx & 127;
    dst[((size_t)(n*WW + w)*HH + h)*CIN + cg*128 + ci] = tile[ci][w];
  }
}

// ---------------- MFMA GEMM: qkv[b][o][h] = sum_c w[o][c] * xtk[b][h][c] ----------------
// BM=128 (o), BN=112 (2 b's x 56 h), BK=32.  4 waves: wave w -> rows w*32..+31.
// B staged in LDS in fragment-granule order: granule g=(k8*112+j) holds
// xtk[b0+j/56][j%56][k0+k8*8 .. +7]  (16B).  A loaded global->VGPR (W is L2-resident).
__global__ __launch_bounds__(256) void kGemmQKV(const void* __restrict__ wq, const bf16* __restrict__ xtk,
                                                bf16* __restrict__ qkv, const int* __restrict__ dflag){
  const bool f32 = (*dflag != 0);
  const int o0 = blockIdx.x * 128;
  const int b0 = blockIdx.y * 2;
  const int t  = threadIdx.x;
  const int lane = t & 63, wv = t >> 6;
  const int q16 = lane >> 4, l16 = lane & 15;

  __shared__ unsigned short Bs[448*8];   // 7168 ushorts = 14336 B

  // ---- B staging: thread t handles granule g1=t and (t<192) g2=t+256
  const int g1 = t, g2 = t + 256;
  const int k81 = g1 / 112, j1 = g1 - k81*112;
  const int k82 = g2 / 112, j2 = g2 - k82*112;
  const int bs1 = (j1 >= 56), bs2 = (j2 >= 56);
  const unsigned short* pB1 = (const unsigned short*)xtk
      + ((size_t)(b0 + bs1)*HH + (j1 - 56*bs1))*CIN + k81*8;
  const unsigned short* pB2 = (const unsigned short*)xtk
      + ((size_t)(b0 + bs2)*HH + (j2 - 56*bs2))*CIN + k82*8;
  const bool has2 = (t < 192);

  // ---- A addresses: lane row = o0 + wv*32 + mt*16 + l16, k = k0 + q16*8
  const size_t aofs0 = (size_t)(o0 + wv*32 + l16)*CIN + q16*8;
  const size_t aofs1 = aofs0 + (size_t)16*CIN;

  // prefetch k-step 0
  short8 bA = *(const short8*)pB1;
  short8 bB; if (has2) bB = *(const short8*)pB2;
  short8 a0 = ldW8(wq, f32, aofs0);
  short8 a1 = ldW8(wq, f32, aofs1);

  f32x4 acc[2][7];
  #pragma unroll
  for (int mt = 0; mt < 2; ++mt)
    #pragma unroll
    for (int nt = 0; nt < 7; ++nt) acc[mt][nt] = (f32x4){0.f,0.f,0.f,0.f};

  for (int kk = 0; kk < 16; ++kk){
    *(short8*)&Bs[g1*8] = bA;
    if (has2) *(short8*)&Bs[g2*8] = bB;
    __syncthreads();
    const short8 ca0 = a0, ca1 = a1;
    if (kk < 15){
      const int ko = (kk + 1)*32;
      bA = *(const short8*)(pB1 + ko);
      if (has2) bB = *(const short8*)(pB2 + ko);
      a0 = ldW8(wq, f32, aofs0 + ko);
      a1 = ldW8(wq, f32, aofs1 + ko);
    }
    #pragma unroll
    for (int nt = 0; nt < 7; ++nt){
      const short8 bf = *(const short8*)&Bs[(q16*112 + nt*16 + l16)*8];
      acc[0][nt] = __builtin_amdgcn_mfma_f32_16x16x32_bf16(ca0, bf, acc[0][nt], 0, 0, 0);
      acc[1][nt] = __builtin_amdgcn_mfma_f32_16x16x32_bf16(ca1, bf, acc[1][nt], 0, 0, 0);
    }
    __syncthreads();
  }

  // ---- epilogue: C/D layout col=lane&15, row=q16*4+reg
  unsigned short* dst = (unsigned short*)qkv;
  #pragma unroll
  for (int nt = 0; nt < 7; ++nt){
    const int j  = nt*16 + l16;
    const int bs = (j >= 56);
    const int h  = j - 56*bs;
    #pragma unroll
    for (int mt = 0; mt < 2; ++mt){
      const int orow = o0 + wv*32 + mt*16 + q16*4;
      size_t base = ((size_t)(b0 + bs)*OO + orow)*HH + h;
      #pragma unroll
      for (int r = 0; r < 4; ++r)
        dst[base + (size_t)r*HH] = f2u(acc[mt][nt][r]);
    }
  }
}

// ---------------- per-channel BN stats over [b][o][h] (axes b,h) -> scale/shift ----------------
__global__ __launch_bounds__(256) void kStatO(const bf16* __restrict__ t, const void* __restrict__ gamma,
                                              const void* __restrict__ beta,
                                              float* __restrict__ sc, float* __restrict__ sh,
                                              const int* __restrict__ dflag){
  const bool f32 = (*dflag != 0);
  const int o = blockIdx.x;
  const unsigned short* p = (const unsigned short*)t;
  float s = 0.f, sq = 0.f;
  for (int idx = threadIdx.x; idx < BB*HH; idx += 256){
    int b = idx / HH, h = idx - b*HH;
    float v = u2f(p[((size_t)b*OO + o)*HH + h]);
    s += v; sq += v*v;
  }
  #pragma unroll
  for (int off = 32; off > 0; off >>= 1){ s += __shfl_down(s, off); sq += __shfl_down(sq, off); }
  __shared__ float rs[4], rq[4];
  const int wid = threadIdx.x >> 6;
  if ((threadIdx.x & 63) == 0){ rs[wid] = s; rq[wid] = sq; }
  __syncthreads();
  if (threadIdx.x == 0){
    float S = rs[0]+rs[1]+rs[2]+rs[3], Q = rq[0]+rq[1]+rq[2]+rq[3];
    const float cnt = (float)(BB*HH);
    float mean = S / cnt;
    float var  = Q / cnt - mean*mean;
    float scale = ldin(gamma, o, f32) * rsqrtf(var + EPSV);
    sc[o] = scale; sh[o] = ldin(beta, o, f32) - mean*scale;
  }
}

// ---------------- score pass A: accumulate BN2 stats for qk/qr/kr ----------------
__global__ __launch_bounds__(256) void kS1(const bf16* __restrict__ qkv, const void* __restrict__ rel,
                                           const float* __restrict__ sc1, const float* __restrict__ sh1,
                                           float* __restrict__ s2sum, float* __restrict__ s2sq,
                                           const int* __restrict__ dflag){
  const bool f32 = (*dflag != 0);
  const int b = blockIdx.x, g = blockIdx.y;
  __shared__ float qs[32][HH];
  __shared__ float ks[32][HH];
  __shared__ float rq[32][RL+1];
  __shared__ float rk[32][RL+1];
  const int t = threadIdx.x;
  {
    const unsigned short* qp = (const unsigned short*)qkv + (size_t)(b*OO + g*128)*HH;
    for (int idx = t; idx < 64*HH; idx += 256){
      int c = idx / HH, h = idx - c*HH;
      int o = g*128 + c;
      float v = u2f(qp[(size_t)c*HH + h]) * sc1[o] + sh1[o];
      if (c < 32) qs[c][h] = v; else ks[c-32][h] = v;
    }
    for (int idx = t; idx < 64*RL; idx += 256){
      int c = idx / RL, d = idx - c*RL;
      float v = ldin(rel, (size_t)c*RL + d, f32);
      if (c < 32) rq[c][d] = v; else rk[c-32][d] = v;
    }
  }
  __syncthreads();
  float s[3] = {0.f,0.f,0.f}, q2[3] = {0.f,0.f,0.f};
  if (t < 196){
    const int i0 = (t/14)*4, j0 = (t - (t/14)*14)*4;
    float aqk[16] = {}, aqr[16] = {}, akr[16] = {};
    const int dq = i0 - j0 + 52, dk = j0 - i0 + 52;
    for (int c = 0; c < 32; ++c){
      const float4 qa = *(const float4*)&qs[c][i0];
      const float4 kb = *(const float4*)&ks[c][j0];
      const float qv[4] = {qa.x,qa.y,qa.z,qa.w};
      const float kv[4] = {kb.x,kb.y,kb.z,kb.w};
      float rqv[7], rkv[7];
      #pragma unroll
      for (int m = 0; m < 7; ++m){ rqv[m] = rq[c][dq+m]; rkv[m] = rk[c][dk+m]; }
      #pragma unroll
      for (int di = 0; di < 4; ++di)
        #pragma unroll
        for (int dj = 0; dj < 4; ++dj){
          aqk[di*4+dj] += qv[di]*kv[dj];
          aqr[di*4+dj] += qv[di]*rqv[3+di-dj];
          akr[di*4+dj] += kv[dj]*rkv[3+dj-di];
        }
    }
    #pragma unroll
    for (int m = 0; m < 16; ++m){
      s[0]+=aqk[m]; q2[0]+=aqk[m]*aqk[m];
      s[1]+=aqr[m]; q2[1]+=aqr[m]*aqr[m];
      s[2]+=akr[m]; q2[2]+=akr[m]*akr[m];
    }
  }
  #pragma unroll
  for (int off = 32; off > 0; off >>= 1)
    #pragma unroll
    for (int m = 0; m < 3; ++m){ s[m]+=__shfl_down(s[m],off); q2[m]+=__shfl_down(q2[m],off); }
  __shared__ float red[6][4];
  const int wid = t >> 6;
  if ((t & 63) == 0){
    #pragma unroll
    for (int m = 0; m < 3; ++m){ red[m][wid]=s[m]; red[3+m][wid]=q2[m]; }
  }
  __syncthreads();
  if (t < 6){
    float v = red[t][0]+red[t][1]+red[t][2]+red[t][3];
    int m = t % 3;
    int ch = m*8 + g;                       // stacked channel = s*8 + g
    atomicAdd((t >= 3) ? &s2sq[ch] : &s2sum[ch], v);
  }
}

__global__ void kF2(const float* __restrict__ s2sum, const float* __restrict__ s2sq,
                    const void* __restrict__ gs, const void* __restrict__ bs,
                    float* __restrict__ sc2, float* __restrict__ sh2,
                    const int* __restrict__ dflag){
  const bool f32 = (*dflag != 0);
  const int ch = threadIdx.x;
  if (ch < 24){
    const float cnt = (float)BB * (float)(HH*HH);
    float mean = s2sum[ch] / cnt;
    float var  = s2sq[ch] / cnt - mean*mean;
    float scale = ldin(gs, ch, f32) * rsqrtf(var + EPSV);
    sc2[ch] = scale; sh2[ch] = ldin(bs, ch, f32) - mean*scale;
  }
}

// ---------------- pass B: recompute scores, BN2, softmax, sv/sve ----------------
__global__ __launch_bounds__(256) void kAttn(const bf16* __restrict__ qkv, const void* __restrict__ rel,
                                             const float* __restrict__ sc1, const float* __restrict__ sh1,
                                             const float* __restrict__ sc2, const float* __restrict__ sh2,
                                             bf16* __restrict__ outr, const int* __restrict__ dflag){
  const bool f32 = (*dflag != 0);
  const int b = blockIdx.x, g = blockIdx.y;
  __shared__ __align__(16) unsigned char smem[61376];
  float (*qs)[HH]          = (float(*)[HH])(smem);                 // [32][56]  phase1
  float (*ks)[HH]          = (float(*)[HH])(smem + 7168);          // [32][56]  phase1
  float (*rq)[RL+1]        = (float(*)[RL+1])(smem + 14336);       // [32][112] phase1
  float (*rk)[RL+1]        = (float(*)[RL+1])(smem + 28672);       // [32][112] phase1
  float (*pT)[HH]          = (float(*)[HH])(smem);                 // [56][56]  phase3
  unsigned short (*vT)[68] = (unsigned short(*)[68])(smem + 12544);// [56][68]  phase3
  float (*rv)[RL+1]        = (float(*)[RL+1])(smem + 20160);       // [64][112] phase3
  float (*sim)[HH]         = (float(*)[HH])(smem + 48832);         // [56][56]  persistent
  const int t = threadIdx.x;
  {
    const unsigned short* qp = (const unsigned short*)qkv + (size_t)(b*OO + g*128)*HH;
    for (int idx = t; idx < 64*HH; idx += 256){
      int c = idx / HH, h = idx - c*HH;
      int o = g*128 + c;
      float v = u2f(qp[(size_t)c*HH + h]) * sc1[o] + sh1[o];
      if (c < 32) qs[c][h] = v; else ks[c-32][h] = v;
    }
    for (int idx = t; idx < 64*RL; idx += 256){
      int c = idx / RL, d = idx - c*RL;
      float v = ldin(rel, (size_t)c*RL + d, f32);
      if (c < 32) rq[c][d] = v; else rk[c-32][d] = v;
    }
  }
  __syncthreads();
  if (t < 196){
    const int i0 = (t/14)*4, j0 = (t - (t/14)*14)*4;
    float aqk[16] = {}, aqr[16] = {}, akr[16] = {};
    const int dq = i0 - j0 + 52, dk = j0 - i0 + 52;
    for (int c = 0; c < 32; ++c){
      const float4 qa = *(const float4*)&qs[c][i0];
      const float4 kb = *(const float4*)&ks[c][j0];
      const float qv[4] = {qa.x,qa.y,qa.z,qa.w};
      const float kv[4] = {kb.x,kb.y,kb.z,kb.w};
      float rqv[7], rkv[7];
      #pragma unroll
      for (int m = 0; m < 7; ++m){ rqv[m] = rq[c][dq+m]; rkv[m] = rk[c][dk+m]; }
      #pragma unroll
      for (int di = 0; di < 4; ++di)
        #pragma unroll
        for (int dj = 0; dj < 4; ++dj){
          aqk[di*4+dj] += qv[di]*kv[dj];
          aqr[di*4+dj] += qv[di]*rqv[3+di-dj];
          akr[di*4+dj] += kv[dj]*rkv[3+dj-di];
        }
    }
    const float scqk=sc2[g],    shqk=sh2[g];
    const float scqr=sc2[8+g],  shqr=sh2[8+g];
    const float sckr=sc2[16+g], shkr=sh2[16+g];
    #pragma unroll
    for (int di = 0; di < 4; ++di)
      #pragma unroll
      for (int dj = 0; dj < 4; ++dj)
        sim[i0+di][j0+dj] = aqk[di*4+dj]*scqk+shqk + aqr[di*4+dj]*scqr+shqr + akr[di*4+dj]*sckr+shkr;
  }
  __syncthreads();
  // phase-3 loads overwrite dead phase-1 region
  {
    const unsigned short* vp = (const unsigned short*)qkv + (size_t)(b*OO + g*128 + 64)*HH;
    for (int idx = t; idx < 64*HH; idx += 256){
      int c = idx / HH, j = idx - c*HH;
      int o = g*128 + 64 + c;
      float v = u2f(vp[(size_t)c*HH + j]) * sc1[o] + sh1[o];
      vT[j][c] = f2u(v);
    }
    for (int idx = t; idx < 64*RL; idx += 256){
      int c = idx / RL, d = idx - c*RL;
      rv[c][d] = ldin(rel, (size_t)(64 + c)*RL + d, f32);
    }
  }
  if (t < 224){
    const int r = t >> 2, l4 = t & 3;
    float pvv[14]; float mx = -1e30f;
    #pragma unroll
    for (int m = 0; m < 14; ++m){ pvv[m] = sim[r][l4 + 4*m]; mx = fmaxf(mx, pvv[m]); }
    mx = fmaxf(mx, __shfl_xor(mx, 1)); mx = fmaxf(mx, __shfl_xor(mx, 2));
    float sm = 0.f;
    #pragma unroll
    for (int m = 0; m < 14; ++m){ pvv[m] = __expf(pvv[m] - mx); sm += pvv[m]; }
    sm += __shfl_xor(sm, 1); sm += __shfl_xor(sm, 2);
    const float inv = 1.f / sm;
    #pragma unroll
    for (int m = 0; m < 14; ++m) pT[l4 + 4*m][r] = pvv[m]*inv;
  }
  __syncthreads();
  if (t < 224){
    const int c0 = (t/14)*4, i0 = (t - (t/14)*14)*4;
    float asv[16] = {}, asve[16] = {};
    float win[4][4];
    #pragma unroll
    for (int dc = 0; dc < 4; ++dc)
      #pragma unroll
      for (int m = 0; m < 4; ++m) win[dc][m] = rv[c0+dc][i0+55+m];
    for (int j = 0; j < 56; ++j){
      const float4  p4 = *(const float4*)&pT[j][i0];
      const ushort4 uv = *(const ushort4*)&vT[j][c0];
      const float pp[4] = {p4.x,p4.y,p4.z,p4.w};
      const float vv[4] = {u2f(uv.x),u2f(uv.y),u2f(uv.z),u2f(uv.w)};
      #pragma unroll
      for (int dc = 0; dc < 4; ++dc)
        #pragma unroll
        for (int di = 0; di < 4; ++di){
          asv[dc*4+di]  += vv[dc]*pp[di];
          asve[dc*4+di] += win[dc][di]*pp[di];
        }
      int nb = i0 - j + 54; if (nb < 0) nb = 0;
      #pragma unroll
      for (int dc = 0; dc < 4; ++dc){
        win[dc][3]=win[dc][2]; win[dc][2]=win[dc][1]; win[dc][1]=win[dc][0];
        win[dc][0] = rv[c0+dc][nb];
      }
    }
    unsigned short* op = (unsigned short*)outr + (size_t)b*OO*HH;
    #pragma unroll
    for (int dc = 0; dc < 4; ++dc){
      const int och = (g*64 + c0 + dc)*2;
      *(ushort4*)(op + (size_t)och*HH + i0) =
        make_ushort4(f2u(asv[dc*4+0]),  f2u(asv[dc*4+1]),  f2u(asv[dc*4+2]),  f2u(asv[dc*4+3]));
      *(ushort4*)(op + (size_t)(och+1)*HH + i0) =
        make_ushort4(f2u(asve[dc*4+0]), f2u(asve[dc*4+1]), f2u(asve[dc*4+2]), f2u(asve[dc*4+3]));
    }
  }
}

// ---------------- BN3 + pair-sum + transpose to (N,512,H,W) ----------------
__global__ __launch_bounds__(256) void kOut(const bf16* __restrict__ outr, const float* __restrict__ sc3,
                                            const float* __restrict__ sh3, void* __restrict__ out,
                                            const int* __restrict__ dflag){
  const bool f32 = (*dflag != 0);
  const int p = blockIdx.x, n = blockIdx.y;
  __shared__ float tile[HH][WW+1];
  const unsigned short* ip = (const unsigned short*)outr;
  const float s0 = sc3[2*p], h0 = sh3[2*p], s1 = sc3[2*p+1], h1 = sh3[2*p+1];
  for (int idx = threadIdx.x; idx < HH*WW; idx += 256){
    int w = idx / HH, h = idx - w*HH;
    size_t base = ((size_t)((n*WW + w)*OO) + 2*p)*HH + h;
    float a = u2f(ip[base]);
    float c = u2f(ip[base + HH]);
    tile[h][w] = a*s0 + h0 + c*s1 + h1;
  }
  __syncthreads();
  const size_t obase = ((size_t)(n*512 + p))*HH*WW;
  for (int idx = threadIdx.x; idx < HH*WW; idx += 256){
    int h = idx / WW, w = idx - h*WW;
    float v = tile[h][w];
    if (f32) ((float*)out)[obase + idx] = v;
    else     ((unsigned short*)out)[obase + idx] = f2u(v);
  }
}

extern "C" void kernel_launch(void* const* d_in, const int* in_sizes, int n_in,
                              void* d_out, int out_size, void* d_ws, size_t ws_size,
                              hipStream_t stream){
  (void)in_sizes; (void)n_in; (void)out_size; (void)ws_size;
  const void* x    = d_in[0];
  const void* wqkv = d_in[1];
  const void* rel  = d_in[2];
  const void* gq   = d_in[3];
  const void* bq   = d_in[4];
  const void* gs   = d_in[5];
  const void* bs   = d_in[6];
  const void* go   = d_in[7];
  const void* bo   = d_in[8];

  char* ws = (char*)d_ws;
  const size_t szA = (size_t)BB*OO*HH*2;   // 102,760,448 B
  bf16* xtk  = (bf16*)ws;                  // [B][H][C]   (first 51.4 MB; dead after GEMM)
  bf16* outr = (bf16*)ws;                  // [B][O][H]   (reuses region A)
  bf16* qkv  = (bf16*)(ws + szA);          // [B][O][H]
  float* st  = (float*)(ws + 2*szA);
  float* sc1   = st;
  float* sh1   = st + 1024;
  float* sc3   = st + 2048;
  float* sh3   = st + 3072;
  float* s2sum = st + 4096;  // 24 used (32 padded)
  float* s2sq  = st + 4128;
  float* sc2   = st + 4160;
  float* sh2   = st + 4192;
  int*   flag  = (int*)(st + 4224);

  kDetect <<<1, 128, 0, stream>>>(x, s2sum, flag);
  kTrans  <<<dim3(HH, 4, NN), 256, 0, stream>>>(x, xtk, flag);
  kGemmQKV<<<dim3(8, BB/2), 256, 0, stream>>>(wqkv, xtk, qkv, flag);
  kStatO  <<<OO, 256, 0, stream>>>(qkv, gq, bq, sc1, sh1, flag);
  kS1     <<<dim3(BB, GG), 256, 0, stream>>>(qkv, rel, sc1, sh1, s2sum, s2sq, flag);
  kF2     <<<1, 64, 0, stream>>>(s2sum, s2sq, gs, bs, sc2, sh2, flag);
  kAttn   <<<dim3(BB, GG), 256, 0, stream>>>(qkv, rel, sc1, sh1, sc2, sh2, outr, flag);
  kStatO  <<<OO, 256, 0, stream>>>(outr, go, bo, sc3, sh3, flag);
  kOut    <<<dim3(512, NN), 256, 0, stream>>>(outr, sc3, sh3, d_out, flag);
}

// Round 4
// 1150.621 us; speedup vs baseline: 1.6470x; 1.0935x over previous
//
#include <hip/hip_runtime.h>
#include <hip/hip_bf16.h>

typedef __hip_bfloat16 bf16;
typedef __attribute__((ext_vector_type(8))) short short8;
typedef __attribute__((ext_vector_type(4))) float f32x4;

#define NN   16
#define CIN  512
#define HH   56
#define WW   56
#define BB   (NN*WW)     /* 896 */
#define OO   1024
#define GG   8
#define RL   111         /* 2K-1 */
#define EPSV 1e-5f

// LDS ushort offsets (shared by kScore/kAttn2)
#define OQT 0        /* qT  [64 rows i][40u]  (cols 0..31 = c) */
#define OKT 2560     /* kT  [64 rows j][40u] */
#define ORQ 5120     /* RqT [112 rows d][40u] */
#define ORK 9600     /* RkT [112 rows d][40u] */
// overlay1 (after score MFMAs)
#define OUL 0        /* Ul [56 i][112u d] */
#define OVL 6272     /* Vl [56 j][112u d] */
// overlay2 (after sim build)
#define OP  0        /* P  [64 i][72u j]  */
#define OSP 4608     /* S' [64 i][136u d] */
// kAttn2-only regions
#define OSIM 14080   /* sim f16 [56][60] */
#define OV   17440   /* v  [64 c][72u j] */
#define ORV  22048   /* Rv [64 c][136u d] */

static __device__ __forceinline__ float u2f(unsigned short u){
  union { unsigned int i; float f; } x; x.i = ((unsigned int)u) << 16; return x.f;
}
static __device__ __forceinline__ unsigned short f2u(float f){
  union { float f; unsigned int i; } x; x.f = f;
  unsigned int i = x.i;
  unsigned int r = i + 0x7FFFu + ((i >> 16) & 1u);   // RNE
  return (unsigned short)(r >> 16);
}
static __device__ __forceinline__ float ldin(const void* p, size_t i, bool f32){
  return f32 ? ((const float*)p)[i] : u2f(((const unsigned short*)p)[i]);
}
static __device__ __forceinline__ short8 ldW8(const void* wq, bool f32, size_t elem){
  if (!f32) return *(const short8*)((const unsigned short*)wq + elem);
  const float* p = (const float*)wq + elem;
  float4 a = *(const float4*)p;
  float4 b = *(const float4*)(p + 4);
  short8 r;
  r[0]=(short)f2u(a.x); r[1]=(short)f2u(a.y); r[2]=(short)f2u(a.z); r[3]=(short)f2u(a.w);
  r[4]=(short)f2u(b.x); r[5]=(short)f2u(b.y); r[6]=(short)f2u(b.z); r[7]=(short)f2u(b.w);
  return r;
}

// ---------------- dtype probe + stat zeroing ----------------
__global__ void kDetect(const void* __restrict__ x, float* __restrict__ stats, int* __restrict__ flag){
  const int t = threadIdx.x;     // 128 threads
  if (t < 64) stats[t] = 0.f;
  unsigned short u = ((const unsigned short*)x)[t];
  int e = (u >> 7) & 0xFF;
  int bad = (e < 100 || e > 140) ? 1 : 0;
  __shared__ int cnt;
  if (t == 0) cnt = 0;
  __syncthreads();
  if (bad) atomicAdd(&cnt, 1);
  __syncthreads();
  if (t == 0) *flag = (cnt > 16) ? 1 : 0;   // 1 => inputs are fp32
}

// ---------------- transpose x (N,C,H,W) -> xtk[b=(n*W+w)][h][c] ----------------
__global__ __launch_bounds__(256) void kTrans(const void* __restrict__ x, bf16* __restrict__ xtk,
                                              const int* __restrict__ dflag){
  const bool f32 = (*dflag != 0);
  const int h  = blockIdx.x;       // 56
  const int cg = blockIdx.y;       // 4 groups of 128 channels
  const int n  = blockIdx.z;       // 16
  __shared__ unsigned short tile[128][58];
  const size_t rbase = (((size_t)n*CIN + cg*128)*HH + h)*WW;
  for (int idx = threadIdx.x; idx < 128*WW; idx += 256){
    int ci = idx / WW, w = idx - ci*WW;
    tile[ci][w] = f2u(ldin(x, rbase + (size_t)ci*HH*WW + w, f32));
  }
  __syncthreads();
  unsigned short* dst = (unsigned short*)xtk;
  for (int idx = threadIdx.x; idx < WW*128; idx += 256){
    int w = idx >> 7, ci = idx & 127;
    dst[((size_t)(n*WW + w)*HH + h)*CIN + cg*128 + ci] = tile[ci][w];
  }
}

// ---------------- MFMA GEMM: qkv[b][o][h] = sum_c w[o][c] * xtk[b][h][c] ----------------
__global__ __launch_bounds__(256) void kGemmQKV(const void* __restrict__ wq, const bf16* __restrict__ xtk,
                                                bf16* __restrict__ qkv, const int* __restrict__ dflag){
  const bool f32 = (*dflag != 0);
  const int o0 = blockIdx.x * 128;
  const int b0 = blockIdx.y * 2;
  const int t  = threadIdx.x;
  const int lane = t & 63, wv = t >> 6;
  const int q16 = lane >> 4, l16 = lane & 15;

  __shared__ unsigned short Bs[448*8];

  const int g1 = t, g2 = t + 256;
  const int k81 = g1 / 112, j1 = g1 - k81*112;
  const int k82 = g2 / 112, j2 = g2 - k82*112;
  const int bs1 = (j1 >= 56), bs2 = (j2 >= 56);
  const unsigned short* pB1 = (const unsigned short*)xtk
      + ((size_t)(b0 + bs1)*HH + (j1 - 56*bs1))*CIN + k81*8;
  const unsigned short* pB2 = (const unsigned short*)xtk
      + ((size_t)(b0 + bs2)*HH + (j2 - 56*bs2))*CIN + k82*8;
  const bool has2 = (t < 192);

  const size_t aofs0 = (size_t)(o0 + wv*32 + l16)*CIN + q16*8;
  const size_t aofs1 = aofs0 + (size_t)16*CIN;

  short8 bA = *(const short8*)pB1;
  short8 bB; if (has2) bB = *(const short8*)pB2;
  short8 a0 = ldW8(wq, f32, aofs0);
  short8 a1 = ldW8(wq, f32, aofs1);

  f32x4 acc[2][7];
  #pragma unroll
  for (int mt = 0; mt < 2; ++mt)
    #pragma unroll
    for (int nt = 0; nt < 7; ++nt) acc[mt][nt] = (f32x4){0.f,0.f,0.f,0.f};

  for (int kk = 0; kk < 16; ++kk){
    *(short8*)&Bs[g1*8] = bA;
    if (has2) *(short8*)&Bs[g2*8] = bB;
    __syncthreads();
    const short8 ca0 = a0, ca1 = a1;
    if (kk < 15){
      const int ko = (kk + 1)*32;
      bA = *(const short8*)(pB1 + ko);
      if (has2) bB = *(const short8*)(pB2 + ko);
      a0 = ldW8(wq, f32, aofs0 + ko);
      a1 = ldW8(wq, f32, aofs1 + ko);
    }
    #pragma unroll
    for (int nt = 0; nt < 7; ++nt){
      const short8 bf = *(const short8*)&Bs[(q16*112 + nt*16 + l16)*8];
      acc[0][nt] = __builtin_amdgcn_mfma_f32_16x16x32_bf16(ca0, bf, acc[0][nt], 0, 0, 0);
      acc[1][nt] = __builtin_amdgcn_mfma_f32_16x16x32_bf16(ca1, bf, acc[1][nt], 0, 0, 0);
    }
    __syncthreads();
  }

  unsigned short* dst = (unsigned short*)qkv;
  #pragma unroll
  for (int nt = 0; nt < 7; ++nt){
    const int j  = nt*16 + l16;
    const int bs = (j >= 56);
    const int h  = j - 56*bs;
    #pragma unroll
    for (int mt = 0; mt < 2; ++mt){
      const int orow = o0 + wv*32 + mt*16 + q16*4;
      size_t base = ((size_t)(b0 + bs)*OO + orow)*HH + h;
      #pragma unroll
      for (int r = 0; r < 4; ++r)
        dst[base + (size_t)r*HH] = f2u(acc[mt][nt][r]);
    }
  }
}

// ---------------- per-channel BN stats over [b][o][h] -> scale/shift ----------------
__global__ __launch_bounds__(256) void kStatO(const bf16* __restrict__ t, const void* __restrict__ gamma,
                                              const void* __restrict__ beta,
                                              float* __restrict__ sc, float* __restrict__ sh,
                                              const int* __restrict__ dflag){
  const bool f32 = (*dflag != 0);
  const int o = blockIdx.x;
  const unsigned short* p = (const unsigned short*)t;
  float s = 0.f, sq = 0.f;
  for (int idx = threadIdx.x; idx < BB*HH; idx += 256){
    int b = idx / HH, h = idx - b*HH;
    float v = u2f(p[((size_t)b*OO + o)*HH + h]);
    s += v; sq += v*v;
  }
  #pragma unroll
  for (int off = 32; off > 0; off >>= 1){ s += __shfl_down(s, off); sq += __shfl_down(sq, off); }
  __shared__ float rs[4], rq[4];
  const int wid = threadIdx.x >> 6;
  if ((threadIdx.x & 63) == 0){ rs[wid] = s; rq[wid] = sq; }
  __syncthreads();
  if (threadIdx.x == 0){
    float S = rs[0]+rs[1]+rs[2]+rs[3], Q = rq[0]+rq[1]+rq[2]+rq[3];
    const float cnt = (float)(BB*HH);
    float mean = S / cnt;
    float var  = Q / cnt - mean*mean;
    float scale = ldin(gamma, o, f32) * rsqrtf(var + EPSV);
    sc[o] = scale; sh[o] = ldin(beta, o, f32) - mean*scale;
  }
}

// ============ shared device helpers for score phase (kScore / kAttn2) ============
static __device__ __forceinline__ void loadQKRel(unsigned short* sm, const bf16* qkv, const void* rel,
                                                 const float* sc1, const float* sh1,
                                                 int b, int g, int t, bool f32){
  const unsigned short* qp = (const unsigned short*)qkv + (size_t)(b*OO + g*128)*HH;
  for (int idx = t; idx < 64*HH; idx += 256){
    int c = idx / HH, h = idx - c*HH;
    int o = g*128 + c;
    float v = u2f(qp[(size_t)c*HH + h]) * sc1[o] + sh1[o];
    sm[(c < 32 ? OQT : OKT) + h*40 + (c & 31)] = f2u(v);
  }
  for (int idx = t; idx < 2*8*40; idx += 256){
    int a = idx / 320, r = idx - a*320;
    sm[(a ? OKT : OQT) + 56*40 + r] = 0;
  }
  for (int idx = t; idx < 64*RL; idx += 256){
    int c = idx / RL, d = idx - c*RL;
    float v = ldin(rel, (size_t)c*RL + d, f32);
    sm[(c < 32 ? ORQ : ORK) + d*40 + (c & 31)] = f2u(v);
  }
  for (int idx = t; idx < 2*40; idx += 256){
    int a = idx / 40, r = idx - a*40;
    sm[(a ? ORK : ORQ) + RL*40 + r] = 0;
  }
}

// ---------------- kScore: MFMA scores -> BN2 stats (no score store) ----------------
__global__ __launch_bounds__(256) void kScore(const bf16* __restrict__ qkv, const void* __restrict__ rel,
                                              const float* __restrict__ sc1, const float* __restrict__ sh1,
                                              float* __restrict__ s2sum, float* __restrict__ s2sq,
                                              const int* __restrict__ dflag){
  const bool f32 = (*dflag != 0);
  const int b = blockIdx.x, g = blockIdx.y;
  __shared__ __align__(16) unsigned short sm[14080];
  __shared__ float red[6][4];
  const int t = threadIdx.x;
  const int lane = t & 63, w = t >> 6;
  const int q16 = lane >> 4, l16 = lane & 15;

  loadQKRel(sm, qkv, rel, sc1, sh1, b, g, t, f32);
  __syncthreads();

  const short8 aq = *(const short8*)&sm[OQT + (w*16 + l16)*40 + q16*8];
  const short8 ak = *(const short8*)&sm[OKT + (w*16 + l16)*40 + q16*8];
  f32x4 aqk[4], aU[7], aV[7];
  #pragma unroll
  for (int nt = 0; nt < 4; ++nt) aqk[nt] = (f32x4){0.f,0.f,0.f,0.f};
  #pragma unroll
  for (int nt = 0; nt < 7; ++nt){ aU[nt] = (f32x4){0.f,0.f,0.f,0.f}; aV[nt] = (f32x4){0.f,0.f,0.f,0.f}; }
  #pragma unroll
  for (int nt = 0; nt < 4; ++nt){
    const short8 bk = *(const short8*)&sm[OKT + (nt*16 + l16)*40 + q16*8];
    aqk[nt] = __builtin_amdgcn_mfma_f32_16x16x32_bf16(aq, bk, aqk[nt], 0, 0, 0);
  }
  #pragma unroll
  for (int nt = 0; nt < 7; ++nt){
    const short8 bq = *(const short8*)&sm[ORQ + (nt*16 + l16)*40 + q16*8];
    const short8 br = *(const short8*)&sm[ORK + (nt*16 + l16)*40 + q16*8];
    aU[nt] = __builtin_amdgcn_mfma_f32_16x16x32_bf16(aq, bq, aU[nt], 0, 0, 0);
    aV[nt] = __builtin_amdgcn_mfma_f32_16x16x32_bf16(ak, br, aV[nt], 0, 0, 0);
  }
  __syncthreads();

  float s0=0.f,s1=0.f,s2=0.f,p0=0.f,p1=0.f,p2=0.f;
  #pragma unroll
  for (int nt = 0; nt < 4; ++nt){
    const int j = nt*16 + l16;
    #pragma unroll
    for (int r = 0; r < 4; ++r){
      const int i = w*16 + q16*4 + r;
      if (i < HH && j < HH){ float v = aqk[nt][r]; s0 += v; p0 += v*v; }
    }
  }
  #pragma unroll
  for (int nt = 0; nt < 7; ++nt){
    const int d = nt*16 + l16;
    #pragma unroll
    for (int r = 0; r < 4; ++r){
      const int i = w*16 + q16*4 + r;
      if (i < HH){
        sm[OUL + i*112 + d] = f2u(aU[nt][r]);
        sm[OVL + i*112 + d] = f2u(aV[nt][r]);
      }
    }
  }
  __syncthreads();
  for (int idx = t; idx < HH*HH; idx += 256){
    int i = idx / HH, j = idx - i*HH;
    float qr = u2f(sm[OUL + i*112 + (i - j + 55)]); s1 += qr; p1 += qr*qr;
    float kr = u2f(sm[OVL + j*112 + (j - i + 55)]); s2 += kr; p2 += kr*kr;
  }
  float s[3] = {s0,s1,s2}, q2[3] = {p0,p1,p2};
  #pragma unroll
  for (int off = 32; off > 0; off >>= 1)
    #pragma unroll
    for (int m = 0; m < 3; ++m){ s[m]+=__shfl_down(s[m],off); q2[m]+=__shfl_down(q2[m],off); }
  if ((t & 63) == 0){
    #pragma unroll
    for (int m = 0; m < 3; ++m){ red[m][w] = s[m]; red[3+m][w] = q2[m]; }
  }
  __syncthreads();
  if (t < 6){
    float v = red[t][0]+red[t][1]+red[t][2]+red[t][3];
    int m = t % 3;
    int ch = m*8 + g;
    atomicAdd((t >= 3) ? &s2sq[ch] : &s2sum[ch], v);
  }
}

__global__ void kF2(const float* __restrict__ s2sum, const float* __restrict__ s2sq,
                    const void* __restrict__ gs, const void* __restrict__ bs,
                    float* __restrict__ sc2, float* __restrict__ sh2,
                    const int* __restrict__ dflag){
  const bool f32 = (*dflag != 0);
  const int ch = threadIdx.x;
  if (ch < 24){
    const float cnt = (float)BB * (float)(HH*HH);
    float mean = s2sum[ch] / cnt;
    float var  = s2sq[ch] / cnt - mean*mean;
    float scale = ldin(gs, ch, f32) * rsqrtf(var + EPSV);
    sc2[ch] = scale; sh2[ch] = ldin(bs, ch, f32) - mean*scale;
  }
}

// ---------------- kAttn2: scores (MFMA) -> BN2 -> softmax -> PV (MFMA) ----------------
__global__ __launch_bounds__(256) void kAttn2(const bf16* __restrict__ qkv, const void* __restrict__ rel,
                                              const float* __restrict__ sc1, const float* __restrict__ sh1,
                                              const float* __restrict__ sc2, const float* __restrict__ sh2,
                                              bf16* __restrict__ outr, const int* __restrict__ dflag){
  const bool f32 = (*dflag != 0);
  const int b = blockIdx.x, g = blockIdx.y;
  __shared__ __align__(16) unsigned short sm[30752];
  const int t = threadIdx.x;
  const int lane = t & 63, w = t >> 6;
  const int q16 = lane >> 4, l16 = lane & 15;

  // phase 1: all global->LDS loads
  loadQKRel(sm, qkv, rel, sc1, sh1, b, g, t, f32);
  {
    const unsigned short* vp = (const unsigned short*)qkv + (size_t)(b*OO + g*128 + 64)*HH;
    for (int idx = t; idx < 64*HH; idx += 256){
      int c = idx / HH, j = idx - c*HH;
      int o = g*128 + 64 + c;
      float v = u2f(vp[(size_t)c*HH + j]) * sc1[o] + sh1[o];
      sm[OV + c*72 + j] = f2u(v);
    }
    for (int idx = t; idx < 64*8; idx += 256){
      int c = idx >> 3, j = 56 + (idx & 7);
      sm[OV + c*72 + j] = 0;
    }
    for (int idx = t; idx < 64*RL; idx += 256){
      int c = idx / RL, d = idx - c*RL;
      sm[ORV + c*136 + d] = f2u(ldin(rel, (size_t)(64 + c)*RL + d, f32));
    }
    for (int idx = t; idx < 64*17; idx += 256){
      int c = idx / 17, d = RL + idx - (idx/17)*17;
      sm[ORV + c*136 + d] = 0;
    }
  }
  __syncthreads();

  // phase 2: score MFMAs
  const short8 aq = *(const short8*)&sm[OQT + (w*16 + l16)*40 + q16*8];
  const short8 ak = *(const short8*)&sm[OKT + (w*16 + l16)*40 + q16*8];
  f32x4 aqk[4], aU[7], aV[7];
  #pragma unroll
  for (int nt = 0; nt < 4; ++nt) aqk[nt] = (f32x4){0.f,0.f,0.f,0.f};
  #pragma unroll
  for (int nt = 0; nt < 7; ++nt){ aU[nt] = (f32x4){0.f,0.f,0.f,0.f}; aV[nt] = (f32x4){0.f,0.f,0.f,0.f}; }
  #pragma unroll
  for (int nt = 0; nt < 4; ++nt){
    const short8 bk = *(const short8*)&sm[OKT + (nt*16 + l16)*40 + q16*8];
    aqk[nt] = __builtin_amdgcn_mfma_f32_16x16x32_bf16(aq, bk, aqk[nt], 0, 0, 0);
  }
  #pragma unroll
  for (int nt = 0; nt < 7; ++nt){
    const short8 bq = *(const short8*)&sm[ORQ + (nt*16 + l16)*40 + q16*8];
    const short8 br = *(const short8*)&sm[ORK + (nt*16 + l16)*40 + q16*8];
    aU[nt] = __builtin_amdgcn_mfma_f32_16x16x32_bf16(aq, bq, aU[nt], 0, 0, 0);
    aV[nt] = __builtin_amdgcn_mfma_f32_16x16x32_bf16(ak, br, aV[nt], 0, 0, 0);
  }
  __syncthreads();

  // phase 3: Ul/Vl overlay
  #pragma unroll
  for (int nt = 0; nt < 7; ++nt){
    const int d = nt*16 + l16;
    #pragma unroll
    for (int r = 0; r < 4; ++r){
      const int i = w*16 + q16*4 + r;
      if (i < HH){
        sm[OUL + i*112 + d] = f2u(aU[nt][r]);
        sm[OVL + i*112 + d] = f2u(aV[nt][r]);
      }
    }
  }
  __syncthreads();

  // phase 4: sim = BN2(qk)+BN2(qr)+BN2(kr), f16
  {
    const float scqk=sc2[g],    shqk=sh2[g];
    const float scqr=sc2[8+g],  shqr=sh2[8+g];
    const float sckr=sc2[16+g], shkr=sh2[16+g];
    _Float16* simh = (_Float16*)&sm[OSIM];
    #pragma unroll
    for (int nt = 0; nt < 4; ++nt){
      const int j = nt*16 + l16;
      #pragma unroll
      for (int r = 0; r < 4; ++r){
        const int i = w*16 + q16*4 + r;
        if (i < HH && j < HH){
          float qr = u2f(sm[OUL + i*112 + (i - j + 55)]);
          float kr = u2f(sm[OVL + j*112 + (j - i + 55)]);
          float sv_ = aqk[nt][r]*scqk + shqk + qr*scqr + shqr + kr*sckr + shkr;
          simh[i*60 + j] = (_Float16)sv_;
        }
      }
    }
  }
  __syncthreads();

  // phase 5: zero P/S'
  for (int i = t; i < 6656; i += 256) ((unsigned int*)sm)[i] = 0u;
  __syncthreads();

  // phase 6: softmax rows, write P and gathered S'
  if (t < 224){
    const _Float16* simh = (const _Float16*)&sm[OSIM];
    const int r = t >> 2, l4 = t & 3;
    float pvv[14]; float mx = -1e30f;
    #pragma unroll
    for (int m = 0; m < 14; ++m){ pvv[m] = (float)simh[r*60 + l4 + 4*m]; mx = fmaxf(mx, pvv[m]); }
    mx = fmaxf(mx, __shfl_xor(mx, 1)); mx = fmaxf(mx, __shfl_xor(mx, 2));
    float smm = 0.f;
    #pragma unroll
    for (int m = 0; m < 14; ++m){ pvv[m] = __expf(pvv[m] - mx); smm += pvv[m]; }
    smm += __shfl_xor(smm, 1); smm += __shfl_xor(smm, 2);
    const float inv = 1.f / smm;
    #pragma unroll
    for (int m = 0; m < 14; ++m){
      const int j = l4 + 4*m;
      unsigned short pu = f2u(pvv[m]*inv);
      sm[OP  + r*72  + j]            = pu;
      sm[OSP + r*136 + (r - j + 55)] = pu;
    }
  }
  __syncthreads();

  // phase 7: PV MFMAs
  f32x4 asv[4], asve[4];
  #pragma unroll
  for (int nt = 0; nt < 4; ++nt){ asv[nt] = (f32x4){0.f,0.f,0.f,0.f}; asve[nt] = (f32x4){0.f,0.f,0.f,0.f}; }
  #pragma unroll
  for (int kk = 0; kk < 2; ++kk){
    const short8 ap = *(const short8*)&sm[OP + (w*16 + l16)*72 + kk*32 + q16*8];
    #pragma unroll
    for (int nt = 0; nt < 4; ++nt){
      const short8 bv = *(const short8*)&sm[OV + (nt*16 + l16)*72 + kk*32 + q16*8];
      asv[nt] = __builtin_amdgcn_mfma_f32_16x16x32_bf16(ap, bv, asv[nt], 0, 0, 0);
    }
  }
  #pragma unroll
  for (int kk = 0; kk < 4; ++kk){
    const short8 as_ = *(const short8*)&sm[OSP + (w*16 + l16)*136 + kk*32 + q16*8];
    #pragma unroll
    for (int nt = 0; nt < 4; ++nt){
      const short8 br = *(const short8*)&sm[ORV + (nt*16 + l16)*136 + kk*32 + q16*8];
      asve[nt] = __builtin_amdgcn_mfma_f32_16x16x32_bf16(as_, br, asve[nt], 0, 0, 0);
    }
  }

  // epilogue: outr[b][(g*64+c)*2 (+1)][h=i]
  const int i0 = w*16 + q16*4;
  if (i0 < HH){
    unsigned short* op = (unsigned short*)outr + (size_t)b*OO*HH;
    #pragma unroll
    for (int nt = 0; nt < 4; ++nt){
      const int c = nt*16 + l16;
      const int och = (g*64 + c)*2;
      *(ushort4*)(op + (size_t)och*HH + i0) =
        make_ushort4(f2u(asv[nt][0]),  f2u(asv[nt][1]),  f2u(asv[nt][2]),  f2u(asv[nt][3]));
      *(ushort4*)(op + (size_t)(och+1)*HH + i0) =
        make_ushort4(f2u(asve[nt][0]), f2u(asve[nt][1]), f2u(asve[nt][2]), f2u(asve[nt][3]));
    }
  }
}

// ---------------- BN3 + pair-sum + transpose to (N,512,H,W) ----------------
__global__ __launch_bounds__(256) void kOut(const bf16* __restrict__ outr, const float* __restrict__ sc3,
                                            const float* __restrict__ sh3, void* __restrict__ out,
                                            const int* __restrict__ dflag){
  const bool f32 = (*dflag != 0);
  const int p = blockIdx.x, n = blockIdx.y;
  __shared__ float tile[HH][WW+1];
  const unsigned short* ip = (const unsigned short*)outr;
  const float s0 = sc3[2*p], h0 = sh3[2*p], s1 = sc3[2*p+1], h1 = sh3[2*p+1];
  for (int idx = threadIdx.x; idx < HH*WW; idx += 256){
    int w = idx / HH, h = idx - w*HH;
    size_t base = ((size_t)((n*WW + w)*OO) + 2*p)*HH + h;
    float a = u2f(ip[base]);
    float c = u2f(ip[base + HH]);
    tile[h][w] = a*s0 + h0 + c*s1 + h1;
  }
  __syncthreads();
  const size_t obase = ((size_t)(n*512 + p))*HH*WW;
  for (int idx = threadIdx.x; idx < HH*WW; idx += 256){
    int h = idx / WW, w = idx - h*WW;
    float v = tile[h][w];
    if (f32) ((float*)out)[obase + idx] = v;
    else     ((unsigned short*)out)[obase + idx] = f2u(v);
  }
}

extern "C" void kernel_launch(void* const* d_in, const int* in_sizes, int n_in,
                              void* d_out, int out_size, void* d_ws, size_t ws_size,
                              hipStream_t stream){
  (void)in_sizes; (void)n_in; (void)out_size; (void)ws_size;
  const void* x    = d_in[0];
  const void* wqkv = d_in[1];
  const void* rel  = d_in[2];
  const void* gq   = d_in[3];
  const void* bq   = d_in[4];
  const void* gs   = d_in[5];
  const void* bs   = d_in[6];
  const void* go   = d_in[7];
  const void* bo   = d_in[8];

  char* ws = (char*)d_ws;
  const size_t szA = (size_t)BB*OO*HH*2;   // 102,760,448 B
  bf16* xtk  = (bf16*)ws;                  // [B][H][C]   (dead after GEMM)
  bf16* outr = (bf16*)ws;                  // [B][O][H]   (reuses region A)
  bf16* qkv  = (bf16*)(ws + szA);          // [B][O][H]
  float* st  = (float*)(ws + 2*szA);
  float* sc1   = st;
  float* sh1   = st + 1024;
  float* sc3   = st + 2048;
  float* sh3   = st + 3072;
  float* s2sum = st + 4096;
  float* s2sq  = st + 4128;
  float* sc2   = st + 4160;
  float* sh2   = st + 4192;
  int*   flag  = (int*)(st + 4224);

  kDetect <<<1, 128, 0, stream>>>(x, s2sum, flag);
  kTrans  <<<dim3(HH, 4, NN), 256, 0, stream>>>(x, xtk, flag);
  kGemmQKV<<<dim3(8, BB/2), 256, 0, stream>>>(wqkv, xtk, qkv, flag);
  kStatO  <<<OO, 256, 0, stream>>>(qkv, gq, bq, sc1, sh1, flag);
  kScore  <<<dim3(BB, GG), 256, 0, stream>>>(qkv, rel, sc1, sh1, s2sum, s2sq, flag);
  kF2     <<<1, 64, 0, stream>>>(s2sum, s2sq, gs, bs, sc2, sh2, flag);
  kAttn2  <<<dim3(BB, GG), 256, 0, stream>>>(qkv, rel, sc1, sh1, sc2, sh2, outr, flag);
  kStatO  <<<OO, 256, 0, stream>>>(outr, go, bo, sc3, sh3, flag);
  kOut    <<<dim3(512, NN), 256, 0, stream>>>(outr, sc3, sh3, d_out, flag);
}

// Round 5
// 833.502 us; speedup vs baseline: 2.2736x; 1.3805x over previous
//
#include <hip/hip_runtime.h>
#include <hip/hip_bf16.h>

typedef __hip_bfloat16 bf16;
typedef __attribute__((ext_vector_type(8))) short short8;
typedef __attribute__((ext_vector_type(4))) float f32x4;

#define NN   16
#define CIN  512
#define HH   56
#define WW   56
#define BB   (NN*WW)     /* 896 */
#define OO   1024
#define GG   8
#define RL   111         /* 2K-1 */
#define EPSV 1e-5f

// ---- shared LDS layout for kScore/kAttn2 (ushort offsets) ----
#define A2_QT  0         /* qT  [64 rows h][40u] cols c0..31          */
#define A2_KT  2560      /* kT  [64][40u]                              */
#define A2_RQ  5120      /* RqT [112 rows d][40u]                      */
#define A2_RK  9600      /* RkT [112][40u]   (inputs end 14080)        */
#define A2_UL  0         /* Ul [56 i][112u d]  overlay after phase 2   */
#define A2_VL  6272      /* Vl [56][112u]      (end 12544)             */
#define A2_P   0         /* P  [64 i][72u j]   overlay after phase 4   */
#define A2_SP  4608      /* S' [64 i][136u d]  (end 13312)             */
#define A2_SIM 14080     /* sim f16 [56][60]   (end 17440)             */
#define A2_VH  13312     /* v half [32 c][72u j]  phase 7 (end 15616)  */
#define A2_RVH 15616     /* Rv half [32 c][136u d] phase 7 (end 19968) */
#define A2_TOT 19968     /* 39936 B -> 4 blocks/CU                     */

// relpad (ws) ushort offsets
#define RP_RQ 0          /* [112][40]  4480u */
#define RP_RK 4480       /* [112][40]  4480u */
#define RP_RV 8960       /* [64][136]  8704u  (end 17664) */

static __device__ __forceinline__ float u2f(unsigned short u){
  union { unsigned int i; float f; } x; x.i = ((unsigned int)u) << 16; return x.f;
}
static __device__ __forceinline__ unsigned short f2u(float f){
  union { float f; unsigned int i; } x; x.f = f;
  unsigned int i = x.i;
  unsigned int r = i + 0x7FFFu + ((i >> 16) & 1u);   // RNE
  return (unsigned short)(r >> 16);
}
static __device__ __forceinline__ float ldin(const void* p, size_t i, bool f32){
  return f32 ? ((const float*)p)[i] : u2f(((const unsigned short*)p)[i]);
}
static __device__ __forceinline__ short8 ldW8(const void* wq, bool f32, size_t elem){
  if (!f32) return *(const short8*)((const unsigned short*)wq + elem);
  const float* p = (const float*)wq + elem;
  float4 a = *(const float4*)p;
  float4 b = *(const float4*)(p + 4);
  short8 r;
  r[0]=(short)f2u(a.x); r[1]=(short)f2u(a.y); r[2]=(short)f2u(a.z); r[3]=(short)f2u(a.w);
  r[4]=(short)f2u(b.x); r[5]=(short)f2u(b.y); r[6]=(short)f2u(b.z); r[7]=(short)f2u(b.w);
  return r;
}

// ---------------- dtype probe + stat zeroing ----------------
__global__ void kDetect(const void* __restrict__ x, float* __restrict__ stats, int* __restrict__ flag){
  const int t = threadIdx.x;     // 128 threads
  if (t < 64) stats[t] = 0.f;
  unsigned short u = ((const unsigned short*)x)[t];
  int e = (u >> 7) & 0xFF;
  int bad = (e < 100 || e > 140) ? 1 : 0;
  __shared__ int cnt;
  if (t == 0) cnt = 0;
  __syncthreads();
  if (bad) atomicAdd(&cnt, 1);
  __syncthreads();
  if (t == 0) *flag = (cnt > 16) ? 1 : 0;   // 1 => inputs are fp32
}

// ---------------- build padded/transposed rel images in ws (once) ----------------
__global__ __launch_bounds__(256) void kPrep(const void* __restrict__ rel, unsigned short* __restrict__ relpad,
                                             const int* __restrict__ dflag){
  const bool f32 = (*dflag != 0);
  const int t = threadIdx.x;
  for (int i = t; i < 8960; i += 256){          // RqT / RkT  [d][c]
    int reg = i / 4480, r = i - reg*4480;
    int d = r / 40, c = r - d*40;
    float v = (d < RL && c < 32) ? ldin(rel, (size_t)(reg*32 + c)*RL + d, f32) : 0.f;
    relpad[i] = f2u(v);
  }
  for (int i = t; i < 8704; i += 256){          // Rv [c][d]
    int c = i / 136, d = i - c*136;
    float v = (d < RL) ? ldin(rel, (size_t)(64 + c)*RL + d, f32) : 0.f;
    relpad[RP_RV + i] = f2u(v);
  }
}

// ---------------- transpose x (N,C,H,W) -> xtk[b=(n*W+w)][h][c] ----------------
__global__ __launch_bounds__(256) void kTrans(const void* __restrict__ x, bf16* __restrict__ xtk,
                                              const int* __restrict__ dflag){
  const bool f32 = (*dflag != 0);
  const int h  = blockIdx.x;       // 56
  const int cg = blockIdx.y;       // 4 groups of 128 channels
  const int n  = blockIdx.z;       // 16
  __shared__ unsigned short tile[128][58];
  const size_t rbase = (((size_t)n*CIN + cg*128)*HH + h)*WW;
  for (int idx = threadIdx.x; idx < 128*WW; idx += 256){
    int ci = idx / WW, w = idx - ci*WW;
    tile[ci][w] = f2u(ldin(x, rbase + (size_t)ci*HH*WW + w, f32));
  }
  __syncthreads();
  unsigned short* dst = (unsigned short*)xtk;
  for (int idx = threadIdx.x; idx < WW*128; idx += 256){
    int w = idx >> 7, ci = idx & 127;
    dst[((size_t)(n*WW + w)*HH + h)*CIN + cg*128 + ci] = tile[ci][w];
  }
}

// ---------------- MFMA GEMM: qkv[b][o][h] = sum_c w[o][c] * xtk[b][h][c] ----------------
__global__ __launch_bounds__(256) void kGemmQKV(const void* __restrict__ wq, const bf16* __restrict__ xtk,
                                                bf16* __restrict__ qkv, const int* __restrict__ dflag){
  const bool f32 = (*dflag != 0);
  const int o0 = blockIdx.x * 128;
  const int b0 = blockIdx.y * 2;
  const int t  = threadIdx.x;
  const int lane = t & 63, wv = t >> 6;
  const int q16 = lane >> 4, l16 = lane & 15;

  __shared__ unsigned short Bs[448*8];

  const int g1 = t, g2 = t + 256;
  const int k81 = g1 / 112, j1 = g1 - k81*112;
  const int k82 = g2 / 112, j2 = g2 - k82*112;
  const int bs1 = (j1 >= 56), bs2 = (j2 >= 56);
  const unsigned short* pB1 = (const unsigned short*)xtk
      + ((size_t)(b0 + bs1)*HH + (j1 - 56*bs1))*CIN + k81*8;
  const unsigned short* pB2 = (const unsigned short*)xtk
      + ((size_t)(b0 + bs2)*HH + (j2 - 56*bs2))*CIN + k82*8;
  const bool has2 = (t < 192);

  const size_t aofs0 = (size_t)(o0 + wv*32 + l16)*CIN + q16*8;
  const size_t aofs1 = aofs0 + (size_t)16*CIN;

  short8 bA = *(const short8*)pB1;
  short8 bB; if (has2) bB = *(const short8*)pB2;
  short8 a0 = ldW8(wq, f32, aofs0);
  short8 a1 = ldW8(wq, f32, aofs1);

  f32x4 acc[2][7];
  #pragma unroll
  for (int mt = 0; mt < 2; ++mt)
    #pragma unroll
    for (int nt = 0; nt < 7; ++nt) acc[mt][nt] = (f32x4){0.f,0.f,0.f,0.f};

  for (int kk = 0; kk < 16; ++kk){
    *(short8*)&Bs[g1*8] = bA;
    if (has2) *(short8*)&Bs[g2*8] = bB;
    __syncthreads();
    const short8 ca0 = a0, ca1 = a1;
    if (kk < 15){
      const int ko = (kk + 1)*32;
      bA = *(const short8*)(pB1 + ko);
      if (has2) bB = *(const short8*)(pB2 + ko);
      a0 = ldW8(wq, f32, aofs0 + ko);
      a1 = ldW8(wq, f32, aofs1 + ko);
    }
    #pragma unroll
    for (int nt = 0; nt < 7; ++nt){
      const short8 bf = *(const short8*)&Bs[(q16*112 + nt*16 + l16)*8];
      acc[0][nt] = __builtin_amdgcn_mfma_f32_16x16x32_bf16(ca0, bf, acc[0][nt], 0, 0, 0);
      acc[1][nt] = __builtin_amdgcn_mfma_f32_16x16x32_bf16(ca1, bf, acc[1][nt], 0, 0, 0);
    }
    __syncthreads();
  }

  unsigned short* dst = (unsigned short*)qkv;
  #pragma unroll
  for (int nt = 0; nt < 7; ++nt){
    const int j  = nt*16 + l16;
    const int bs = (j >= 56);
    const int h  = j - 56*bs;
    #pragma unroll
    for (int mt = 0; mt < 2; ++mt){
      const int orow = o0 + wv*32 + mt*16 + q16*4;
      size_t base = ((size_t)(b0 + bs)*OO + orow)*HH + h;
      #pragma unroll
      for (int r = 0; r < 4; ++r)
        dst[base + (size_t)r*HH] = f2u(acc[mt][nt][r]);
    }
  }
}

// ---------------- per-channel BN stats over [b][o][h] -> scale/shift ----------------
__global__ __launch_bounds__(256) void kStatO(const bf16* __restrict__ t, const void* __restrict__ gamma,
                                              const void* __restrict__ beta,
                                              float* __restrict__ sc, float* __restrict__ sh,
                                              const int* __restrict__ dflag){
  const bool f32 = (*dflag != 0);
  const int o = blockIdx.x;
  const unsigned short* p = (const unsigned short*)t;
  float s = 0.f, sq = 0.f;
  for (int q = threadIdx.x; q < BB*14; q += 256){
    int b = q / 14, hq = q - b*14;
    ushort4 u = *(const ushort4*)(p + ((size_t)b*OO + o)*HH + hq*4);
    float v0 = u2f(u.x), v1 = u2f(u.y), v2 = u2f(u.z), v3 = u2f(u.w);
    s  += (v0 + v1) + (v2 + v3);
    sq += (v0*v0 + v1*v1) + (v2*v2 + v3*v3);
  }
  #pragma unroll
  for (int off = 32; off > 0; off >>= 1){ s += __shfl_down(s, off); sq += __shfl_down(sq, off); }
  __shared__ float rs[4], rq[4];
  const int wid = threadIdx.x >> 6;
  if ((threadIdx.x & 63) == 0){ rs[wid] = s; rq[wid] = sq; }
  __syncthreads();
  if (threadIdx.x == 0){
    float S = rs[0]+rs[1]+rs[2]+rs[3], Q = rq[0]+rq[1]+rq[2]+rq[3];
    const float cnt = (float)(BB*HH);
    float mean = S / cnt;
    float var  = Q / cnt - mean*mean;
    float scale = ldin(gamma, o, f32) * rsqrtf(var + EPSV);
    sc[o] = scale; sh[o] = ldin(beta, o, f32) - mean*scale;
  }
}

// ============ shared helpers: staging + score MFMAs ============
static __device__ __forceinline__ void loadQK(unsigned short* sm, const unsigned short* qkv,
                                              const float* __restrict__ sc1, const float* __restrict__ sh1,
                                              const unsigned short* __restrict__ relpad,
                                              int b, int g, int t){
  const unsigned short* qp = qkv + (size_t)(b*OO + g*128)*HH;
  for (int q = t; q < 896; q += 256){           // q/k rows, ushort4
    int c = q / 14, hq = q - c*14;
    int o = g*128 + c;
    ushort4 u = *(const ushort4*)(qp + (size_t)c*HH + hq*4);
    float s = sc1[o], hb = sh1[o];
    int base = (c < 32 ? A2_QT : A2_KT) + (c & 31) + hq*160;
    sm[base]       = f2u(u2f(u.x)*s + hb);
    sm[base + 40]  = f2u(u2f(u.y)*s + hb);
    sm[base + 80]  = f2u(u2f(u.z)*s + hb);
    sm[base + 120] = f2u(u2f(u.w)*s + hb);
  }
  for (int i = t; i < 640; i += 256){           // zero rows 56..63 of qT/kT
    int a = i / 320, r = i - a*320;
    sm[(a ? A2_KT : A2_QT) + 2240 + r] = 0;
  }
  for (int q = t; q < 2240; q += 256)           // RqT+RkT padded copy
    *(ushort4*)&sm[A2_RQ + q*4] = *(const ushort4*)(relpad + q*4);
}

static __device__ __forceinline__ void scoreMFMA(const unsigned short* sm, int w, int q16, int l16,
                                                 f32x4 aqk[4], f32x4 aU[7], f32x4 aV[7]){
  const short8 aq = *(const short8*)&sm[A2_QT + (w*16 + l16)*40 + q16*8];
  const short8 ak = *(const short8*)&sm[A2_KT + (w*16 + l16)*40 + q16*8];
  #pragma unroll
  for (int nt = 0; nt < 4; ++nt){
    const short8 bk = *(const short8*)&sm[A2_KT + (nt*16 + l16)*40 + q16*8];
    aqk[nt] = __builtin_amdgcn_mfma_f32_16x16x32_bf16(aq, bk, aqk[nt], 0, 0, 0);
  }
  #pragma unroll
  for (int nt = 0; nt < 7; ++nt){
    const short8 bq = *(const short8*)&sm[A2_RQ + (nt*16 + l16)*40 + q16*8];
    const short8 br = *(const short8*)&sm[A2_RK + (nt*16 + l16)*40 + q16*8];
    aU[nt] = __builtin_amdgcn_mfma_f32_16x16x32_bf16(aq, bq, aU[nt], 0, 0, 0);
    aV[nt] = __builtin_amdgcn_mfma_f32_16x16x32_bf16(ak, br, aV[nt], 0, 0, 0);
  }
}

static __device__ __forceinline__ void writeUV(unsigned short* sm, int w, int q16, int l16,
                                               const f32x4 aU[7], const f32x4 aV[7]){
  #pragma unroll
  for (int nt = 0; nt < 7; ++nt){
    const int d = nt*16 + l16;
    #pragma unroll
    for (int r = 0; r < 4; ++r){
      const int i = w*16 + q16*4 + r;
      if (i < HH){
        sm[A2_UL + i*112 + d] = f2u(aU[nt][r]);
        sm[A2_VL + i*112 + d] = f2u(aV[nt][r]);
      }
    }
  }
}

// ---------------- kScore: MFMA scores -> BN2 stats ----------------
__global__ __launch_bounds__(256) void kScore(const bf16* __restrict__ qkv,
                                              const unsigned short* __restrict__ relpad,
                                              const float* __restrict__ sc1, const float* __restrict__ sh1,
                                              float* __restrict__ s2sum, float* __restrict__ s2sq){
  const int b = blockIdx.x, g = blockIdx.y;
  __shared__ __align__(16) unsigned short sm[14080];
  __shared__ float red[6][4];
  const int t = threadIdx.x;
  const int lane = t & 63, w = t >> 6;
  const int q16 = lane >> 4, l16 = lane & 15;

  loadQK(sm, (const unsigned short*)qkv, sc1, sh1, relpad, b, g, t);
  __syncthreads();

  f32x4 aqk[4], aU[7], aV[7];
  #pragma unroll
  for (int nt = 0; nt < 4; ++nt) aqk[nt] = (f32x4){0.f,0.f,0.f,0.f};
  #pragma unroll
  for (int nt = 0; nt < 7; ++nt){ aU[nt] = (f32x4){0.f,0.f,0.f,0.f}; aV[nt] = (f32x4){0.f,0.f,0.f,0.f}; }
  scoreMFMA(sm, w, q16, l16, aqk, aU, aV);
  __syncthreads();

  float s0=0.f,s1=0.f,s2=0.f,p0=0.f,p1=0.f,p2=0.f;
  #pragma unroll
  for (int nt = 0; nt < 4; ++nt){
    const int j = nt*16 + l16;
    #pragma unroll
    for (int r = 0; r < 4; ++r){
      const int i = w*16 + q16*4 + r;
      if (i < HH && j < HH){ float v = aqk[nt][r]; s0 += v; p0 += v*v; }
    }
  }
  writeUV(sm, w, q16, l16, aU, aV);
  __syncthreads();
  for (int idx = t; idx < HH*HH; idx += 256){
    int i = idx / HH, j = idx - i*HH;
    float qr = u2f(sm[A2_UL + i*112 + (i - j + 55)]); s1 += qr; p1 += qr*qr;
    float kr = u2f(sm[A2_VL + j*112 + (j - i + 55)]); s2 += kr; p2 += kr*kr;
  }
  float s[3] = {s0,s1,s2}, q2[3] = {p0,p1,p2};
  #pragma unroll
  for (int off = 32; off > 0; off >>= 1)
    #pragma unroll
    for (int m = 0; m < 3; ++m){ s[m]+=__shfl_down(s[m],off); q2[m]+=__shfl_down(q2[m],off); }
  if ((t & 63) == 0){
    #pragma unroll
    for (int m = 0; m < 3; ++m){ red[m][w] = s[m]; red[3+m][w] = q2[m]; }
  }
  __syncthreads();
  if (t < 6){
    float v = red[t][0]+red[t][1]+red[t][2]+red[t][3];
    int m = t % 3;
    int ch = m*8 + g;
    atomicAdd((t >= 3) ? &s2sq[ch] : &s2sum[ch], v);
  }
}

__global__ void kF2(const float* __restrict__ s2sum, const float* __restrict__ s2sq,
                    const void* __restrict__ gs, const void* __restrict__ bs,
                    float* __restrict__ sc2, float* __restrict__ sh2,
                    const int* __restrict__ dflag){
  const bool f32 = (*dflag != 0);
  const int ch = threadIdx.x;
  if (ch < 24){
    const float cnt = (float)BB * (float)(HH*HH);
    float mean = s2sum[ch] / cnt;
    float var  = s2sq[ch] / cnt - mean*mean;
    float scale = ldin(gs, ch, f32) * rsqrtf(var + EPSV);
    sc2[ch] = scale; sh2[ch] = ldin(bs, ch, f32) - mean*scale;
  }
}

// ---------------- kAttn2: scores -> BN2 -> softmax -> PV ----------------
__global__ __launch_bounds__(256) void kAttn2(const bf16* __restrict__ qkv,
                                              const unsigned short* __restrict__ relpad,
                                              const float* __restrict__ sc1, const float* __restrict__ sh1,
                                              const float* __restrict__ sc2, const float* __restrict__ sh2,
                                              bf16* __restrict__ outr){
  const int b = blockIdx.x, g = blockIdx.y;
  __shared__ __align__(16) unsigned short sm[A2_TOT];
  const int t = threadIdx.x;
  const int lane = t & 63, w = t >> 6;
  const int q16 = lane >> 4, l16 = lane & 15;

  // phase 1: q/k + rel staging
  loadQK(sm, (const unsigned short*)qkv, sc1, sh1, relpad, b, g, t);
  __syncthreads();

  // phase 2: score MFMAs
  f32x4 aqk[4], aU[7], aV[7];
  #pragma unroll
  for (int nt = 0; nt < 4; ++nt) aqk[nt] = (f32x4){0.f,0.f,0.f,0.f};
  #pragma unroll
  for (int nt = 0; nt < 7; ++nt){ aU[nt] = (f32x4){0.f,0.f,0.f,0.f}; aV[nt] = (f32x4){0.f,0.f,0.f,0.f}; }
  scoreMFMA(sm, w, q16, l16, aqk, aU, aV);
  __syncthreads();

  // phase 3: Ul/Vl overlay
  writeUV(sm, w, q16, l16, aU, aV);
  __syncthreads();

  // phase 4: sim = BN2(qk)+BN2(qr)+BN2(kr), f16
  {
    const float scqk=sc2[g],    shqk=sh2[g];
    const float scqr=sc2[8+g],  shqr=sh2[8+g];
    const float sckr=sc2[16+g], shkr=sh2[16+g];
    _Float16* simh = (_Float16*)&sm[A2_SIM];
    #pragma unroll
    for (int nt = 0; nt < 4; ++nt){
      const int j = nt*16 + l16;
      #pragma unroll
      for (int r = 0; r < 4; ++r){
        const int i = w*16 + q16*4 + r;
        if (i < HH && j < HH){
          float qr = u2f(sm[A2_UL + i*112 + (i - j + 55)]);
          float kr = u2f(sm[A2_VL + j*112 + (j - i + 55)]);
          float sv_ = aqk[nt][r]*scqk + shqk + qr*scqr + shqr + kr*sckr + shkr;
          simh[i*60 + j] = (_Float16)sv_;
        }
      }
    }
  }
  __syncthreads();

  // phase 5: zero P/S' (13312u = 6656 dwords)
  for (int i = t; i < 6656; i += 256) ((unsigned int*)sm)[i] = 0u;
  __syncthreads();

  // phase 6: softmax rows -> P and gathered S'
  if (t < 224){
    const _Float16* simh = (const _Float16*)&sm[A2_SIM];
    const int r = t >> 2, l4 = t & 3;
    float pvv[14]; float mx = -1e30f;
    #pragma unroll
    for (int m = 0; m < 14; ++m){ pvv[m] = (float)simh[r*60 + l4 + 4*m]; mx = fmaxf(mx, pvv[m]); }
    mx = fmaxf(mx, __shfl_xor(mx, 1)); mx = fmaxf(mx, __shfl_xor(mx, 2));
    float smm = 0.f;
    #pragma unroll
    for (int m = 0; m < 14; ++m){ pvv[m] = __expf(pvv[m] - mx); smm += pvv[m]; }
    smm += __shfl_xor(smm, 1); smm += __shfl_xor(smm, 2);
    const float inv = 1.f / smm;
    #pragma unroll
    for (int m = 0; m < 14; ++m){
      const int j = l4 + 4*m;
      unsigned short pu = f2u(pvv[m]*inv);
      sm[A2_P  + r*72  + j]            = pu;
      sm[A2_SP + r*136 + (r - j + 55)] = pu;
    }
  }
  __syncthreads();

  // phase 7: PV in two c-halves (v/Rv staged late into dead sim region)
  f32x4 asv[4], asve[4];
  #pragma unroll
  for (int nt = 0; nt < 4; ++nt){ asv[nt] = (f32x4){0.f,0.f,0.f,0.f}; asve[nt] = (f32x4){0.f,0.f,0.f,0.f}; }
  const short8 ap0 = *(const short8*)&sm[A2_P + (w*16 + l16)*72 + q16*8];
  const short8 ap1 = *(const short8*)&sm[A2_P + (w*16 + l16)*72 + 32 + q16*8];
  short8 asp[4];
  #pragma unroll
  for (int kk = 0; kk < 4; ++kk)
    asp[kk] = *(const short8*)&sm[A2_SP + (w*16 + l16)*136 + kk*32 + q16*8];

  #pragma unroll
  for (int half = 0; half < 2; ++half){
    // stage v half: 32 rows x 56 j (+ zero cols 56..63)
    const unsigned short* vp = (const unsigned short*)qkv
        + ((size_t)b*OO + g*128 + 64 + half*32)*HH;
    for (int q = t; q < 448; q += 256){
      int c2 = q / 14, hq = q - c2*14;
      int o = g*128 + 64 + half*32 + c2;
      ushort4 u = *(const ushort4*)(vp + (size_t)c2*HH + hq*4);
      float s = sc1[o], hb = sh1[o];
      unsigned short* d = &sm[A2_VH + c2*72 + hq*4];
      d[0] = f2u(u2f(u.x)*s + hb);
      d[1] = f2u(u2f(u.y)*s + hb);
      d[2] = f2u(u2f(u.z)*s + hb);
      d[3] = f2u(u2f(u.w)*s + hb);
    }
    if (t < 256){ int c2 = t >> 3, e = t & 7; sm[A2_VH + c2*72 + 56 + e] = 0; }
    // stage Rv half: aligned ushort4 copy of 32x136
    {
      const unsigned short* rvsrc = relpad + RP_RV + half*32*136;
      for (int q = t; q < 1088; q += 256)
        *(ushort4*)&sm[A2_RVH + q*4] = *(const ushort4*)(rvsrc + q*4);
    }
    __syncthreads();
    #pragma unroll
    for (int ntl = 0; ntl < 2; ++ntl){
      const int nt = half*2 + ntl;
      const short8 bv0 = *(const short8*)&sm[A2_VH + (ntl*16 + l16)*72 + q16*8];
      const short8 bv1 = *(const short8*)&sm[A2_VH + (ntl*16 + l16)*72 + 32 + q16*8];
      asv[nt] = __builtin_amdgcn_mfma_f32_16x16x32_bf16(ap0, bv0, asv[nt], 0, 0, 0);
      asv[nt] = __builtin_amdgcn_mfma_f32_16x16x32_bf16(ap1, bv1, asv[nt], 0, 0, 0);
      #pragma unroll
      for (int kk = 0; kk < 4; ++kk){
        const short8 br = *(const short8*)&sm[A2_RVH + (ntl*16 + l16)*136 + kk*32 + q16*8];
        asve[nt] = __builtin_amdgcn_mfma_f32_16x16x32_bf16(asp[kk], br, asve[nt], 0, 0, 0);
      }
    }
    __syncthreads();
  }

  // epilogue
  const int i0 = w*16 + q16*4;
  if (i0 < HH){
    unsigned short* op = (unsigned short*)outr + (size_t)b*OO*HH;
    #pragma unroll
    for (int nt = 0; nt < 4; ++nt){
      const int c = nt*16 + l16;
      const int och = (g*64 + c)*2;
      *(ushort4*)(op + (size_t)och*HH + i0) =
        make_ushort4(f2u(asv[nt][0]),  f2u(asv[nt][1]),  f2u(asv[nt][2]),  f2u(asv[nt][3]));
      *(ushort4*)(op + (size_t)(och+1)*HH + i0) =
        make_ushort4(f2u(asve[nt][0]), f2u(asve[nt][1]), f2u(asve[nt][2]), f2u(asve[nt][3]));
    }
  }
}

// ---------------- BN3 + pair-sum + transpose to (N,512,H,W) ----------------
__global__ __launch_bounds__(256) void kOut(const bf16* __restrict__ outr, const float* __restrict__ sc3,
                                            const float* __restrict__ sh3, void* __restrict__ out,
                                            const int* __restrict__ dflag){
  const bool f32 = (*dflag != 0);
  const int p = blockIdx.x, n = blockIdx.y;
  __shared__ float tile[HH][WW+1];
  const unsigned short* ip = (const unsigned short*)outr;
  const float s0 = sc3[2*p], h0 = sh3[2*p], s1 = sc3[2*p+1], h1 = sh3[2*p+1];
  for (int idx = threadIdx.x; idx < HH*WW; idx += 256){
    int w = idx / HH, h = idx - w*HH;
    size_t base = ((size_t)((n*WW + w)*OO) + 2*p)*HH + h;
    float a = u2f(ip[base]);
    float c = u2f(ip[base + HH]);
    tile[h][w] = a*s0 + h0 + c*s1 + h1;
  }
  __syncthreads();
  const size_t obase = ((size_t)(n*512 + p))*HH*WW;
  for (int idx = threadIdx.x; idx < HH*WW; idx += 256){
    int h = idx / WW, w = idx - h*WW;
    float v = tile[h][w];
    if (f32) ((float*)out)[obase + idx] = v;
    else     ((unsigned short*)out)[obase + idx] = f2u(v);
  }
}

extern "C" void kernel_launch(void* const* d_in, const int* in_sizes, int n_in,
                              void* d_out, int out_size, void* d_ws, size_t ws_size,
                              hipStream_t stream){
  (void)in_sizes; (void)n_in; (void)out_size; (void)ws_size;
  const void* x    = d_in[0];
  const void* wqkv = d_in[1];
  const void* rel  = d_in[2];
  const void* gq   = d_in[3];
  const void* bq   = d_in[4];
  const void* gs   = d_in[5];
  const void* bs   = d_in[6];
  const void* go   = d_in[7];
  const void* bo   = d_in[8];

  char* ws = (char*)d_ws;
  const size_t szA = (size_t)BB*OO*HH*2;   // 102,760,448 B
  bf16* xtk  = (bf16*)ws;                  // [B][H][C]   (dead after GEMM)
  bf16* outr = (bf16*)ws;                  // [B][O][H]   (reuses region A)
  bf16* qkv  = (bf16*)(ws + szA);          // [B][O][H]
  float* st  = (float*)(ws + 2*szA);
  float* sc1   = st;
  float* sh1   = st + 1024;
  float* sc3   = st + 2048;
  float* sh3   = st + 3072;
  float* s2sum = st + 4096;
  float* s2sq  = st + 4128;
  float* sc2   = st + 4160;
  float* sh2   = st + 4192;
  int*   flag  = (int*)(st + 4224);
  unsigned short* relpad = (unsigned short*)(ws + 2*szA + 32768);  // 17664u

  kDetect <<<1, 128, 0, stream>>>(x, s2sum, flag);
  kPrep   <<<1, 256, 0, stream>>>(rel, relpad, flag);
  kTrans  <<<dim3(HH, 4, NN), 256, 0, stream>>>(x, xtk, flag);
  kGemmQKV<<<dim3(8, BB/2), 256, 0, stream>>>(wqkv, xtk, qkv, flag);
  kStatO  <<<OO, 256, 0, stream>>>(qkv, gq, bq, sc1, sh1, flag);
  kScore  <<<dim3(BB, GG), 256, 0, stream>>>(qkv, relpad, sc1, sh1, s2sum, s2sq);
  kF2     <<<1, 64, 0, stream>>>(s2sum, s2sq, gs, bs, sc2, sh2, flag);
  kAttn2  <<<dim3(BB, GG), 256, 0, stream>>>(qkv, relpad, sc1, sh1, sc2, sh2, outr);
  kStatO  <<<OO, 256, 0, stream>>>(outr, go, bo, sc3, sh3, flag);
  kOut    <<<dim3(512, NN), 256, 0, stream>>>(outr, sc3, sh3, d_out, flag);
}